// Round 11
// baseline (111.328 us; speedup 1.0000x reference)
//
#include <hip/hip_runtime.h>

#define NN 2048
#define PP 2048
#define QQ 64
#define GR_ROWS 4
#define GR_SLOTS 80   // 64 quad + g0(slot 64) + 15 pad
#define GR_MT 5       // 16-row M-tiles per row

typedef __attribute__((ext_vector_type(8))) short short8;
typedef __attribute__((ext_vector_type(4))) float f32x4;
typedef __attribute__((ext_vector_type(4))) unsigned u32x4;

union V4 { u32x4 u; short8 s; };

#if __has_builtin(__builtin_amdgcn_exp2f)
#define EXP2(x) __builtin_amdgcn_exp2f(x)
#else
#define EXP2(x) exp2f(x)
#endif

__device__ __forceinline__ float fast_rcp(float x) { return __builtin_amdgcn_rcpf(x); }

// tanh(x) = 1 - 2/(2^(2x*log2e)+1); saturates for |x| large (rcp(inf)=0)
__device__ __forceinline__ float fast_tanh(float x) {
    float t = EXP2(x * 2.885390082f);
    return 1.0f - 2.0f * __builtin_amdgcn_rcpf(t + 1.0f);
}

// Pade(5,4) tanh on 4 values with ONE shared rcp.
// tanh(x) ~= x(945+105u+u^2)/(945+420u+15u^2), u=x^2, x clamped to [-4,4].
// err <= 2.4e-3 (max at clamp). Denominators in [945,11505] -> 4-product <= 1.8e16: safe.
__device__ __forceinline__ void tanh4(const float x0, const float x1,
                                      const float x2, const float x3,
                                      float* __restrict__ h) {
    float n[4], d[4];
    const float xs[4] = {x0, x1, x2, x3};
    #pragma unroll
    for (int j = 0; j < 4; ++j) {
        const float xc = fminf(fmaxf(xs[j], -4.0f), 4.0f);
        const float u = xc * xc;
        n[j] = fmaf(u + 105.0f, u, 945.0f) * xc;
        d[j] = fmaf(fmaf(15.0f, u, 420.0f), u, 945.0f);
    }
    const float p1 = d[0]*d[1], p2 = p1*d[2], p3 = p2*d[3];
    const float R  = fast_rcp(p3);
    const float i3 = R*p2,  R2 = R*d[3];
    const float i2 = R2*p1, R1 = R2*d[2];
    const float i1 = R1*d[0], i0 = R1*d[1];
    h[0] = n[0]*i0; h[1] = n[1]*i1; h[2] = n[2]*i2; h[3] = n[3]*i3;
}

// packed f32x2 -> bf16x2 (RNE), single instruction
__device__ __forceinline__ unsigned cvt_pk_bf16(float lo, float hi) {
    unsigned r;
    asm("v_cvt_pk_bf16_f32 %0, %1, %2" : "=v"(r) : "v"(lo), "v"(hi));
    return r;
}
// scalar RNE bf16 bits (for single stores)
__device__ __forceinline__ unsigned short bf16_bits(float f) {
    unsigned u = __builtin_bit_cast(unsigned, f);
    u += 0x7FFFu + ((u >> 16) & 1u);
    return (unsigned short)(u >> 16);
}

// ==== Path A, kernel A1: wave = 256-p chunk; fixed-bound softmax accumulated in-kernel ==
// grid: 8192 x 128 (2 waves). row n = bid>>2, chunk = (bid&3)*2 + w. No barriers/atomics.
__global__ __launch_bounds__(128) void attn_logits_kernel(
    const float* __restrict__ pc, const float* __restrict__ cp,
    const float* __restrict__ cv,
    const float* __restrict__ w1, const float* __restrict__ b1,
    const float* __restrict__ w2, const float* __restrict__ b2,
    const float* __restrict__ w3, const float* __restrict__ b3,
    float4* __restrict__ partials)   // (NN, 8) chunk partials {s,q0,q1,0}
{
    __shared__ float2 sap[2][256];          // wave-private (angl,pos)
    __shared__ unsigned short sidx[2][256]; // wave-private p-index

    const int t = threadIdx.x;
    const int w = t >> 6, lane = t & 63;
    const int c15 = lane & 15, kg = lane >> 4;
    const int k0 = kg * 8;
    const int n  = blockIdx.x >> 2;
    const int chunk = (blockIdx.x & 3) * 2 + w;
    const int p0 = chunk * 256;

    const float b3v = b3[0];
    const float x0 = pc[n*4+0], x1 = pc[n*4+1];
    const float v0 = pc[n*4+2], v1 = pc[n*4+3];
    const float rinv = __builtin_amdgcn_rsqf(v0*v0 + v1*v1 + 1e-16f);
    const float a0 = v0 * rinv, a1 = v1 * rinv;

    // ---- step 1: compact survivors of this wave's 256-p chunk ----
    int cnt = 0;
    #pragma unroll
    for (int i = 0; i < 4; ++i) {
        const int p = p0 + i*64 + lane;
        const float2 cpp = ((const float2*)cp)[p];
        const float r0 = x0 - cpp.x;
        const float r1 = x1 - cpp.y;
        const float pos = fmaf(r0, a0, r1*a1);
        const bool f = pos > 0.0f;
        const unsigned long long mask = __ballot(f);
        if (f) {
            const int idx = cnt + __popcll(mask & ((1ull << lane) - 1ull));
            const float dist = sqrtf(r0*r0 + r1*r1 + 1e-16f);
            const float angl = pos * fast_rcp(dist + 1e-8f);
            sap[w][idx]  = make_float2(angl, pos);
            sidx[w][idx] = (unsigned short)p;
        }
        cnt += __popcll(mask);              // wave-uniform
    }

    // ---- row-invariant fragments ----
    union BF { short8 s8; unsigned u[4]; } B0, B1;
    #pragma unroll
    for (int j2 = 0; j2 < 4; ++j2) {
        const int ka = k0 + 2*j2, kb = ka + 1;
        B0.u[j2] = cvt_pk_bf16(w2[ka*32 + c15],      w2[kb*32 + c15]);
        B1.u[j2] = cvt_pk_bf16(w2[ka*32 + c15 + 16], w2[kb*32 + c15 + 16]);
    }
    float b2a[4], b2b[4], w3a[4], w3b[4];
    #pragma unroll
    for (int r = 0; r < 4; ++r) {
        b2a[r] = b2[kg*4 + r];      b2b[r] = b2[16 + kg*4 + r];
        w3a[r] = w3[kg*4 + r];      w3b[r] = w3[16 + kg*4 + r];
    }
    float cfrag[8], w1a[8], w1b[8];
    #pragma unroll
    for (int j = 0; j < 8; ++j) {
        const int k = k0 + j;
        float c = b1[k];
        c = fmaf(x0, w1[0*32+k], c);
        c = fmaf(x1, w1[1*32+k], c);
        c = fmaf(v0, w1[2*32+k], c);
        c = fmaf(v1, w1[3*32+k], c);
        cfrag[j] = c;
        w1a[j] = w1[4*32+k];
        w1b[j] = w1[5*32+k];
    }
    // rigorous logit bound: |lg partial| <= 1.005*sum|w3| (|tanh~|<=1.0017), full += b3
    float sw3 = 0.0f;
    #pragma unroll
    for (int j = 0; j < 32; ++j) sw3 += fabsf(w3[j]);
    const float Lb = fabsf(b3v) + 1.005f * sw3;
    const float C_E = (b3v - Lb) * 1.44269504f;   // e = exp2(lg*log2e + C_E) <= 1

    // ---- step 2: MFMA tiles over survivors; accumulate softmax partials ----
    float s = 0.0f, q0 = 0.0f, q1 = 0.0f;
    const int nt = (cnt + 15) >> 4;
    #pragma unroll 2
    for (int tile = 0; tile < nt; ++tile) {
        const int li = tile*16 + c15;
        const float2 ap = sap[w][li < cnt ? li : 0];
        const float angl = ap.x, pos = ap.y;

        // h1 pre-activations (8) then Pade tanh in two rcp-shared groups
        float pre[8], h[8];
        #pragma unroll
        for (int j = 0; j < 8; ++j)
            pre[j] = fmaf(angl, w1a[j], fmaf(pos, w1b[j], cfrag[j]));
        tanh4(pre[0], pre[1], pre[2], pre[3], &h[0]);
        tanh4(pre[4], pre[5], pre[6], pre[7], &h[4]);

        union AF { short8 s8; unsigned u[4]; } H;
        #pragma unroll
        for (int j2 = 0; j2 < 4; ++j2)
            H.u[j2] = cvt_pk_bf16(h[2*j2], h[2*j2+1]);

        // D = W2^T · H1^T : col = pair (c15), row = neuron (kg*4+r)
        f32x4 acca = {b2a[0], b2a[1], b2a[2], b2a[3]};
        f32x4 accb = {b2b[0], b2b[1], b2b[2], b2b[3]};
        acca = __builtin_amdgcn_mfma_f32_16x16x32_bf16(B0.s8, H.s8, acca, 0, 0, 0);
        accb = __builtin_amdgcn_mfma_f32_16x16x32_bf16(B1.s8, H.s8, accb, 0, 0, 0);

        float ha[4], hb[4];
        tanh4(acca[0], acca[1], acca[2], acca[3], ha);
        tanh4(accb[0], accb[1], accb[2], accb[3], hb);

        float lg = 0.0f;
        #pragma unroll
        for (int r = 0; r < 4; ++r) {
            lg = fmaf(ha[r], w3a[r], lg);
            lg = fmaf(hb[r], w3b[r], lg);
        }
        lg += __shfl_xor(lg, 16);
        lg += __shfl_xor(lg, 32);   // all 64 lanes now hold the full partial for pair c15

        // fixed-bound softmax accumulation (kg==0 lanes only contribute)
        const bool val = (kg == 0) && (li < cnt);
        const int pidx = val ? (int)sidx[w][li] : 0;
        const float2 cvv = ((const float2*)cv)[pidx];
        const float e = val ? EXP2(fmaf(lg, 1.44269504f, C_E)) : 0.0f;
        s += e;
        q0 = fmaf(e, cvv.x, q0);
        q1 = fmaf(e, cvv.y, q1);
    }

    // wave reduce + store chunk partial
    #pragma unroll
    for (int off = 1; off < 64; off <<= 1) {
        s  += __shfl_xor(s, off);
        q0 += __shfl_xor(q0, off);
        q1 += __shfl_xor(q1, off);
    }
    if (lane == 0) partials[n*8 + chunk] = make_float4(s, q0, q1, 0.0f);
}

// ==== Path A, kernel A2: reduce chunk partials -> coeff =====================
__global__ __launch_bounds__(256) void attn_coeff_kernel(
    const float4* __restrict__ partials, const float* __restrict__ cv,
    float* __restrict__ coeff_out)
{
    const int n = blockIdx.x * 256 + threadIdx.x;
    float S = 0.0f, Q0 = 0.0f, Q1 = 0.0f;
    #pragma unroll
    for (int c = 0; c < 8; ++c) {
        const float4 P = partials[n*8 + c];
        S += P.x; Q0 += P.y; Q1 += P.z;
    }
    if (!(S > 0.0f)) {   // all masked -> uniform softmax (e=1 per slot)
        S = (float)PP; Q0 = 0.0f; Q1 = 0.0f;
        for (int p = 0; p < PP; ++p) {
            Q0 += cv[2*p]; Q1 += cv[2*p+1];
        }
    }
    const float invS = fast_rcp(S);
    coeff_out[n*2+0] = __expf(-Q0 * invS);
    coeff_out[n*2+1] = __expf(-Q1 * invS);
}

// ======== Path B (fallback, ws too small): R9 attn kernel, verified ========
__global__ __launch_bounds__(256) void attn_kernel(
    const float* __restrict__ pc, const float* __restrict__ cp,
    const float* __restrict__ cv,
    const float* __restrict__ w1, const float* __restrict__ b1,
    const float* __restrict__ w2, const float* __restrict__ b2,
    const float* __restrict__ w3, const float* __restrict__ b3,
    float* __restrict__ coeff_out)
{
    __shared__ float2 scpc[PP];
    __shared__ unsigned short slist[PP];
    __shared__ float sred[16];
    __shared__ int scount;

    const int n = blockIdx.x;
    const int t = threadIdx.x;
    const int wid  = t >> 6;
    const int lane = t & 63;
    const int c15  = lane & 15;
    const int kg   = lane >> 4;
    const int k0   = kg * 8;

    const float b3v = b3[0];

    if (t == 0) scount = 0;

    const float x0 = pc[n*4+0], x1 = pc[n*4+1];
    const float v0 = pc[n*4+2], v1 = pc[n*4+3];
    const float rinv = __builtin_amdgcn_rsqf(v0*v0 + v1*v1 + 1e-16f);
    const float a0 = v0 * rinv, a1 = v1 * rinv;

    union BF { short8 s8; unsigned u[4]; } B0, B1;
    #pragma unroll
    for (int j2 = 0; j2 < 4; ++j2) {
        const int ka = k0 + 2*j2, kb = ka + 1;
        B0.u[j2] = cvt_pk_bf16(w2[ka*32 + c15],      w2[kb*32 + c15]);
        B1.u[j2] = cvt_pk_bf16(w2[ka*32 + c15 + 16], w2[kb*32 + c15 + 16]);
    }
    float b2a[4], b2b[4], w3a[4], w3b[4];
    #pragma unroll
    for (int r = 0; r < 4; ++r) {
        b2a[r] = b2[kg*4 + r];      b2b[r] = b2[16 + kg*4 + r];
        w3a[r] = w3[kg*4 + r];      w3b[r] = w3[16 + kg*4 + r];
    }
    float cfrag[8], w1a[8], w1b[8];
    #pragma unroll
    for (int j = 0; j < 8; ++j) {
        const int k = k0 + j;
        float c = b1[k];
        c = fmaf(x0, w1[0*32+k], c);
        c = fmaf(x1, w1[1*32+k], c);
        c = fmaf(v0, w1[2*32+k], c);
        c = fmaf(v1, w1[3*32+k], c);
        cfrag[j] = c;
        w1a[j] = w1[4*32+k];
        w1b[j] = w1[5*32+k];
    }
    __syncthreads();

    #pragma unroll 1
    for (int i = 0; i < PP/256; ++i) {
        const int p = i*256 + t;
        const float2 cpp = ((const float2*)cp)[p];
        const float r0 = x0 - cpp.x;
        const float r1 = x1 - cpp.y;
        const float pos = fmaf(r0, a0, r1*a1);
        const bool f = pos > 0.0f;
        const unsigned long long mask = __ballot(f);
        int base = 0;
        if (lane == 0 && mask) base = atomicAdd(&scount, __popcll(mask));
        base = __shfl(base, 0);
        if (f) {
            const int idx = base + __popcll(mask & ((1ull << lane) - 1ull));
            const float dist = sqrtf(r0*r0 + r1*r1 + 1e-16f);
            const float angl = pos * fast_rcp(dist + 1e-8f);
            slist[idx] = (unsigned short)p;
            scpc[idx] = make_float2(angl, pos);
        }
    }
    __syncthreads();
    const int M  = scount;
    const int Mt = (M + 15) >> 4;

    #pragma unroll 2
    for (int tile = wid; tile < Mt; tile += 4) {
        const int li = tile*16 + c15;
        const float2 ap = scpc[li < M ? li : 0];
        const float angl = ap.x, pos = ap.y;

        union AF { short8 s8; unsigned u[4]; } H;
        #pragma unroll
        for (int j2 = 0; j2 < 4; ++j2) {
            const float ha = fast_tanh(fmaf(angl, w1a[2*j2+0], fmaf(pos, w1b[2*j2+0], cfrag[2*j2+0])));
            const float hb = fast_tanh(fmaf(angl, w1a[2*j2+1], fmaf(pos, w1b[2*j2+1], cfrag[2*j2+1])));
            H.u[j2] = cvt_pk_bf16(ha, hb);
        }

        f32x4 acca = {b2a[0], b2a[1], b2a[2], b2a[3]};
        f32x4 accb = {b2b[0], b2b[1], b2b[2], b2b[3]};
        acca = __builtin_amdgcn_mfma_f32_16x16x32_bf16(B0.s8, H.s8, acca, 0, 0, 0);
        accb = __builtin_amdgcn_mfma_f32_16x16x32_bf16(B1.s8, H.s8, accb, 0, 0, 0);

        float lg = 0.0f;
        #pragma unroll
        for (int r = 0; r < 4; ++r) {
            lg = fmaf(fast_tanh(acca[r]), w3a[r], lg);
            lg = fmaf(fast_tanh(accb[r]), w3b[r], lg);
        }
        lg += __shfl_xor(lg, 16);
        lg += __shfl_xor(lg, 32);

        if (kg == 0 && li < M) scpc[li].x = lg + b3v;
    }
    __syncthreads();

    float m = -3.4e38f;
    if (M > 0)
        for (int i = t; i < M; i += 256) m = fmaxf(m, scpc[i].x);
    #pragma unroll
    for (int off = 32; off; off >>= 1) m = fmaxf(m, __shfl_xor(m, off));
    if (lane == 0) sred[wid] = m;
    __syncthreads();
    m = fmaxf(fmaxf(sred[0], sred[1]), fmaxf(sred[2], sred[3]));

    float s = 0.0f, q0 = 0.0f, q1 = 0.0f;
    if (M > 0) {
        #pragma unroll 2
        for (int i = t; i < M; i += 256) {
            const float e = EXP2((scpc[i].x - m) * 1.44269504f);
            const float2 cvv = ((const float2*)cv)[slist[i]];
            s += e;
            q0 = fmaf(e, cvv.x, q0);
            q1 = fmaf(e, cvv.y, q1);
        }
    } else {
        for (int i = t; i < PP; i += 256) {
            const float2 cvv = ((const float2*)cv)[i];
            s += 1.0f; q0 += cvv.x; q1 += cvv.y;
        }
    }
    #pragma unroll
    for (int off = 32; off; off >>= 1) {
        s  += __shfl_xor(s, off);
        q0 += __shfl_xor(q0, off);
        q1 += __shfl_xor(q1, off);
    }
    __syncthreads();
    if (lane == 0) {
        sred[4 + wid*3 + 0] = s;
        sred[4 + wid*3 + 1] = q0;
        sred[4 + wid*3 + 2] = q1;
    }
    __syncthreads();
    if (t == 0) {
        float S = 0.0f, Q0 = 0.0f, Q1 = 0.0f;
        #pragma unroll
        for (int w = 0; w < 4; ++w) {
            S  += sred[4 + w*3 + 0];
            Q0 += sred[4 + w*3 + 1];
            Q1 += sred[4 + w*3 + 2];
        }
        const float invS = fast_rcp(S);
        coeff_out[n*2+0] = __expf(-Q0 * invS);
        coeff_out[n*2+1] = __expf(-Q1 * invS);
    }
}

// ------- Kernel C: green MLP via MFMA. Block = 4 rows, wave = 1 row (80 slots) -------
__global__ __launch_bounds__(256) void green_kernel(
    const float* __restrict__ pc,  const float* __restrict__ bc,
    const float* __restrict__ skc, const float* __restrict__ sk,
    const float* __restrict__ vw,
    const float* __restrict__ gw1, const float* __restrict__ gb1,
    const float* __restrict__ gw2, const float* __restrict__ gb2,
    const float* __restrict__ gw3, const float* __restrict__ gb3,
    const float* __restrict__ rw,  const float* __restrict__ rb,
    const float* __restrict__ fw,  const float* __restrict__ fb,
    const float* __restrict__ coeff,
    float* __restrict__ out)
{
    __shared__ unsigned short sinA[GR_ROWS*GR_SLOTS*16];
    __shared__ unsigned short shb[4][16*64];
    __shared__ float swq[GR_SLOTS];
    __shared__ float sg0[4][64];
    __shared__ float squad[4][64];

    const int t = threadIdx.x;
    const int w = t >> 6, lane = t & 63;
    const int c15 = lane & 15, kg = lane >> 4;
    const int n0 = blockIdx.x * GR_ROWS;

    V4 Bw1[4], Bw2[2][4], Bw3[2][4];
    #pragma unroll
    for (int nt = 0; nt < 4; ++nt) {
        const int col = c15 + nt*16;
        #pragma unroll
        for (int j2 = 0; j2 < 4; ++j2) {
            const int ka = kg*8 + 2*j2, kb = ka + 1;
            const float va = (ka < 10) ? gw1[ka*64 + col] : 0.0f;
            const float vb = (kb < 10) ? gw1[kb*64 + col] : 0.0f;
            Bw1[nt].u[j2] = cvt_pk_bf16(va, vb);
        }
        #pragma unroll
        for (int kt = 0; kt < 2; ++kt) {
            #pragma unroll
            for (int j2 = 0; j2 < 4; ++j2) {
                const int ka = kt*32 + kg*8 + 2*j2, kb = ka + 1;
                Bw2[kt][nt].u[j2] = cvt_pk_bf16(gw2[ka*64 + col], gw2[kb*64 + col]);
                Bw3[kt][nt].u[j2] = cvt_pk_bf16(gw3[ka*64 + col], gw3[kb*64 + col]);
            }
        }
    }
    float b1c[4], b2c[4], b3c[4];
    #pragma unroll
    for (int nt = 0; nt < 4; ++nt) {
        b1c[nt] = gb1[c15 + nt*16];
        b2c[nt] = gb2[c15 + nt*16];
        b3c[nt] = gb3[c15 + nt*16];
    }

    for (int row = t; row < GR_ROWS*GR_SLOTS; row += 256) {
        const int nl = row / GR_SLOTS;
        const int s  = row - nl*GR_SLOTS;
        const int n  = n0 + nl;
        u32x4 lo = {0u,0u,0u,0u}, hi = {0u,0u,0u,0u};
        if (s <= 64) {
            const float X0 = pc[n*4+0], X1 = pc[n*4+1];
            const float V0 = pc[n*4+2], V1 = pc[n*4+3];
            const float XP0 = bc[n*4+0], XP1 = bc[n*4+1];
            float I6, I7;
            if (s == 64) { I6 = bc[n*4+2]; I7 = bc[n*4+3]; }
            else         { I6 = skc[s*2+0]; I7 = skc[s*2+1]; }
            const float C0 = coeff[n*2+0], C1 = coeff[n*2+1];
            lo[0] = cvt_pk_bf16(X0, X1);
            lo[1] = cvt_pk_bf16(V0, V1);
            lo[2] = cvt_pk_bf16(XP0, XP1);
            lo[3] = cvt_pk_bf16(I6, I7);
            hi[0] = cvt_pk_bf16(C0, C1);
        }
        ((u32x4*)sinA)[row*2 + 0] = lo;
        ((u32x4*)sinA)[row*2 + 1] = hi;
    }
    if (t < GR_SLOTS)
        swq[t] = (t < QQ) ? (1.0f - sk[t]) * vw[t] : 0.0f;
    __syncthreads();

    unsigned short* hb = &shb[w][0];
    float qacc[4] = {0.f, 0.f, 0.f, 0.f};

    #pragma unroll 1
    for (int T = 0; T < GR_MT; ++T) {
        const int rm = w*GR_SLOTS + T*16 + c15;
        V4 A1; A1.u = (u32x4){0u,0u,0u,0u};
        if (kg < 2) A1.u = ((u32x4*)sinA)[rm*2 + kg];

        f32x4 acc1[4];
        #pragma unroll
        for (int nt = 0; nt < 4; ++nt) {
            f32x4 a = {b1c[nt], b1c[nt], b1c[nt], b1c[nt]};
            acc1[nt] = __builtin_amdgcn_mfma_f32_16x16x32_bf16(A1.s, Bw1[nt].s, a, 0, 0, 0);
        }
        #pragma unroll
        for (int nt = 0; nt < 4; ++nt) {
            #pragma unroll
            for (int r = 0; r < 4; ++r) {
                const int rl = kg*4 + r;
                hb[rl*64 + ((c15 + nt*16) ^ ((rl&7)<<3))] = bf16_bits(fast_tanh(acc1[nt][r]));
            }
        }
        V4 A2[2];
        #pragma unroll
        for (int kt = 0; kt < 2; ++kt)
            A2[kt].u = ((u32x4*)hb)[(c15*64 + ((kt*32 + kg*8) ^ ((c15&7)<<3))) >> 3];
        f32x4 acc2[4];
        #pragma unroll
        for (int nt = 0; nt < 4; ++nt) {
            f32x4 a = {b2c[nt], b2c[nt], b2c[nt], b2c[nt]};
            a = __builtin_amdgcn_mfma_f32_16x16x32_bf16(A2[0].s, Bw2[0][nt].s, a, 0, 0, 0);
            acc2[nt] = __builtin_amdgcn_mfma_f32_16x16x32_bf16(A2[1].s, Bw2[1][nt].s, a, 0, 0, 0);
        }
        #pragma unroll
        for (int nt = 0; nt < 4; ++nt) {
            #pragma unroll
            for (int r = 0; r < 4; ++r) {
                const int rl = kg*4 + r;
                hb[rl*64 + ((c15 + nt*16) ^ ((rl&7)<<3))] = bf16_bits(fast_tanh(acc2[nt][r]));
            }
        }
        V4 A3[2];
        #pragma unroll
        for (int kt = 0; kt < 2; ++kt)
            A3[kt].u = ((u32x4*)hb)[(c15*64 + ((kt*32 + kg*8) ^ ((c15&7)<<3))) >> 3];
        f32x4 acc3[4];
        #pragma unroll
        for (int nt = 0; nt < 4; ++nt) {
            f32x4 a = {b3c[nt], b3c[nt], b3c[nt], b3c[nt]};
            a = __builtin_amdgcn_mfma_f32_16x16x32_bf16(A3[0].s, Bw3[0][nt].s, a, 0, 0, 0);
            acc3[nt] = __builtin_amdgcn_mfma_f32_16x16x32_bf16(A3[1].s, Bw3[1][nt].s, a, 0, 0, 0);
        }
        #pragma unroll
        for (int r = 0; r < 4; ++r) {
            const int s = T*16 + kg*4 + r;
            const float wq = swq[s];
            #pragma unroll
            for (int nt = 0; nt < 4; ++nt) {
                const float g = __expf(fast_tanh(acc3[nt][r]));
                qacc[nt] = fmaf(wq, g, qacc[nt]);
                if (T == GR_MT-1 && kg == 0 && r == 0) sg0[w][c15 + nt*16] = g;
            }
        }
    }

    #pragma unroll
    for (int nt = 0; nt < 4; ++nt) {
        qacc[nt] += __shfl_xor(qacc[nt], 16);
        qacc[nt] += __shfl_xor(qacc[nt], 32);
    }
    if (kg == 0) {
        #pragma unroll
        for (int nt = 0; nt < 4; ++nt) squad[w][c15 + nt*16] = qacc[nt];
    }

    const int k = lane;
    float r0a = rb[k], r1a = 0.f, r2a = 0.f, r3a = 0.f;
    #pragma unroll
    for (int j = 0; j < 64; j += 4) {
        const float4 qd = *(const float4*)&squad[w][j];
        r0a = fmaf(qd.x, rw[(j+0)*64 + k], r0a);
        r1a = fmaf(qd.y, rw[(j+1)*64 + k], r1a);
        r2a = fmaf(qd.z, rw[(j+2)*64 + k], r2a);
        r3a = fmaf(qd.w, rw[(j+3)*64 + k], r3a);
    }
    const float resv = fast_tanh((r0a + r1a) + (r2a + r3a));
    float term = (sg0[w][k] + resv) * fw[k];
    #pragma unroll
    for (int off = 32; off; off >>= 1) term += __shfl_xor(term, off);
    if (lane == 0) out[n0 + w] = term + fb[0];
}

extern "C" void kernel_launch(void* const* d_in, const int* in_sizes, int n_in,
                              void* d_out, int out_size, void* d_ws, size_t ws_size,
                              hipStream_t stream) {
    const float* pc  = (const float*)d_in[0];
    const float* bc  = (const float*)d_in[1];
    const float* cp  = (const float*)d_in[2];
    const float* cv  = (const float*)d_in[3];
    const float* skc = (const float*)d_in[4];
    const float* sk  = (const float*)d_in[5];
    const float* vw  = (const float*)d_in[6];
    const float* aw1 = (const float*)d_in[7];
    const float* ab1 = (const float*)d_in[8];
    const float* aw2 = (const float*)d_in[9];
    const float* ab2 = (const float*)d_in[10];
    const float* aw3 = (const float*)d_in[11];
    const float* ab3 = (const float*)d_in[12];
    const float* gw1 = (const float*)d_in[13];
    const float* gb1 = (const float*)d_in[14];
    const float* gw2 = (const float*)d_in[15];
    const float* gb2 = (const float*)d_in[16];
    const float* gw3 = (const float*)d_in[17];
    const float* gb3 = (const float*)d_in[18];
    const float* rw  = (const float*)d_in[19];
    const float* rb  = (const float*)d_in[20];
    const float* fw  = (const float*)d_in[21];
    const float* fb  = (const float*)d_in[22];

    float* coeff = (float*)d_ws;                       // 16 KB
    float* outp  = (float*)d_out;

    const size_t need = (size_t)NN*2*sizeof(float) + (size_t)NN*8*sizeof(float4);
    if (ws_size >= need) {
        float4* partials = (float4*)((char*)d_ws + (size_t)NN*2*sizeof(float)); // 256 KB
        attn_logits_kernel<<<NN*4, 128, 0, stream>>>(pc, cp, cv, aw1, ab1, aw2, ab2,
                                                     aw3, ab3, partials);
        attn_coeff_kernel<<<NN/256, 256, 0, stream>>>(partials, cv, coeff);
    } else {
        attn_kernel<<<NN, 256, 0, stream>>>(pc, cp, cv, aw1, ab1, aw2, ab2, aw3, ab3, coeff);
    }
    green_kernel<<<NN/GR_ROWS, 256, 0, stream>>>(pc, bc, skc, sk, vw,
                                                 gw1, gb1, gw2, gb2, gw3, gb3,
                                                 rw, rb, fw, fb, coeff, outp);
}

// Round 12
// 96.561 us; speedup vs baseline: 1.1529x; 1.1529x over previous
//
#include <hip/hip_runtime.h>

#define NN 2048
#define PP 2048
#define QQ 64
#define GR_ROWS 4
#define GR_SLOTS 80   // 64 quad + g0(slot 64) + 15 pad
#define GR_MT 5       // 16-row M-tiles per row

typedef __attribute__((ext_vector_type(8))) short short8;
typedef __attribute__((ext_vector_type(4))) float f32x4;
typedef __attribute__((ext_vector_type(4))) unsigned u32x4;

union V4 { u32x4 u; short8 s; };

#if __has_builtin(__builtin_amdgcn_exp2f)
#define EXP2(x) __builtin_amdgcn_exp2f(x)
#else
#define EXP2(x) exp2f(x)
#endif

__device__ __forceinline__ float fast_rcp(float x) { return __builtin_amdgcn_rcpf(x); }

// tanh(x) = 1 - 2/(2^(2x*log2e)+1); saturates for |x| large (rcp(inf)=0)
__device__ __forceinline__ float fast_tanh(float x) {
    float t = EXP2(x * 2.885390082f);
    return 1.0f - 2.0f * __builtin_amdgcn_rcpf(t + 1.0f);
}

// packed f32x2 -> bf16x2 (RNE), single instruction
__device__ __forceinline__ unsigned cvt_pk_bf16(float lo, float hi) {
    unsigned r;
    asm("v_cvt_pk_bf16_f32 %0, %1, %2" : "=v"(r) : "v"(lo), "v"(hi));
    return r;
}
// scalar RNE bf16 bits (for single stores)
__device__ __forceinline__ unsigned short bf16_bits(float f) {
    unsigned u = __builtin_bit_cast(unsigned, f);
    u += 0x7FFFu + ((u >> 16) & 1u);
    return (unsigned short)(u >> 16);
}

// ==== Path A, kernel A1: wave = 256-p chunk; fused fixed-bound softmax partials ====
// grid: 8192 x 128 (2 waves). row n = bid>>2, chunk = (bid&3)*2 + w. No barriers/atomics.
__global__ __launch_bounds__(128) void attn_logits_kernel(
    const float* __restrict__ pc, const float* __restrict__ cp,
    const float* __restrict__ cv,
    const float* __restrict__ w1, const float* __restrict__ b1,
    const float* __restrict__ w2, const float* __restrict__ b2,
    const float* __restrict__ w3, const float* __restrict__ b3,
    float4* __restrict__ partials)   // (NN, 8) chunk partials {s,q0,q1,0}
{
    __shared__ float2 sap[2][272];          // wave-private (angl,pos), +16 zero pad
    __shared__ unsigned short sidx[2][272]; // wave-private p-index

    const int t = threadIdx.x;
    const int w = t >> 6, lane = t & 63;
    const int c15 = lane & 15, kg = lane >> 4;
    const int k0 = kg * 8;
    const int n  = blockIdx.x >> 2;
    const int chunk = (blockIdx.x & 3) * 2 + w;
    const int p0 = chunk * 256;

    const float b3v = b3[0];
    const float x0 = pc[n*4+0], x1 = pc[n*4+1];
    const float v0 = pc[n*4+2], v1 = pc[n*4+3];
    const float rinv = __builtin_amdgcn_rsqf(v0*v0 + v1*v1 + 1e-16f);
    const float a0 = v0 * rinv, a1 = v1 * rinv;

    // ---- step 1: compact survivors of this wave's 256-p chunk ----
    int cnt = 0;
    #pragma unroll
    for (int i = 0; i < 4; ++i) {
        const int p = p0 + i*64 + lane;
        const float2 cpp = ((const float2*)cp)[p];
        const float r0 = x0 - cpp.x;
        const float r1 = x1 - cpp.y;
        const float pos = fmaf(r0, a0, r1*a1);
        const bool f = pos > 0.0f;
        const unsigned long long mask = __ballot(f);
        if (f) {
            const int idx = cnt + __popcll(mask & ((1ull << lane) - 1ull));
            const float dist = sqrtf(r0*r0 + r1*r1 + 1e-16f);
            const float angl = pos * fast_rcp(dist + 1e-8f);
            sap[w][idx]  = make_float2(angl, pos);
            sidx[w][idx] = (unsigned short)p;
        }
        cnt += __popcll(mask);              // wave-uniform
    }
    // pad 16 entries so tile loads never need an index select
    if (lane < 16) {
        sap[w][cnt + lane]  = make_float2(0.0f, 0.0f);
        sidx[w][cnt + lane] = 0;
    }

    // ---- row-invariant fragments ----
    union BF { short8 s8; unsigned u[4]; } B0, B1;
    #pragma unroll
    for (int j2 = 0; j2 < 4; ++j2) {
        const int ka = k0 + 2*j2, kb = ka + 1;
        B0.u[j2] = cvt_pk_bf16(w2[ka*32 + c15],      w2[kb*32 + c15]);
        B1.u[j2] = cvt_pk_bf16(w2[ka*32 + c15 + 16], w2[kb*32 + c15 + 16]);
    }
    float b2a[4], b2b[4], w3a[4], w3b[4];
    #pragma unroll
    for (int r = 0; r < 4; ++r) {
        b2a[r] = b2[kg*4 + r];      b2b[r] = b2[16 + kg*4 + r];
        w3a[r] = w3[kg*4 + r];      w3b[r] = w3[16 + kg*4 + r];
    }
    float cfrag[8], w1a[8], w1b[8];
    #pragma unroll
    for (int j = 0; j < 8; ++j) {
        const int k = k0 + j;
        float c = b1[k];
        c = fmaf(x0, w1[0*32+k], c);
        c = fmaf(x1, w1[1*32+k], c);
        c = fmaf(v0, w1[2*32+k], c);
        c = fmaf(v1, w1[3*32+k], c);
        cfrag[j] = c;
        w1a[j] = w1[4*32+k];
        w1b[j] = w1[5*32+k];
    }
    // rigorous logit bound: |lg - b3| <= 1.0*sum|w3| (|tanh|<1); e = exp2(lg*l2e + C_E) <= 1
    float sw3 = 0.0f;
    #pragma unroll
    for (int j = 0; j < 32; ++j) sw3 += fabsf(w3[j]);
    const float Lb = fabsf(b3v) + sw3;
    const float C_E = (b3v - Lb) * 1.44269504f;

    // ---- step 2: MFMA tiles over survivors; accumulate softmax partials ----
    float s = 0.0f, q0 = 0.0f, q1 = 0.0f;
    const int nt = (cnt + 15) >> 4;
    #pragma unroll 2
    for (int tile = 0; tile < nt; ++tile) {
        const int li = tile*16 + c15;
        const float2 ap = sap[w][li];       // padded: always in-bounds
        const float angl = ap.x, pos = ap.y;

        float pre[8], h[8];
        #pragma unroll
        for (int j = 0; j < 8; ++j)
            pre[j] = fmaf(angl, w1a[j], fmaf(pos, w1b[j], cfrag[j]));
        #pragma unroll
        for (int j = 0; j < 8; ++j) h[j] = fast_tanh(pre[j]);

        union AF { short8 s8; unsigned u[4]; } H;
        #pragma unroll
        for (int j2 = 0; j2 < 4; ++j2)
            H.u[j2] = cvt_pk_bf16(h[2*j2], h[2*j2+1]);

        // D = W2^T · H1^T : col = pair (c15), row = neuron (kg*4+r)
        f32x4 acca = {b2a[0], b2a[1], b2a[2], b2a[3]};
        f32x4 accb = {b2b[0], b2b[1], b2b[2], b2b[3]};
        acca = __builtin_amdgcn_mfma_f32_16x16x32_bf16(B0.s8, H.s8, acca, 0, 0, 0);
        accb = __builtin_amdgcn_mfma_f32_16x16x32_bf16(B1.s8, H.s8, accb, 0, 0, 0);

        float lg = 0.0f;
        #pragma unroll
        for (int r = 0; r < 4; ++r) {
            lg = fmaf(fast_tanh(acca[r]), w3a[r], lg);
            lg = fmaf(fast_tanh(accb[r]), w3b[r], lg);
        }
        lg += __shfl_xor(lg, 16);
        lg += __shfl_xor(lg, 32);   // full logit partial for pair c15 in all lanes

        const bool val = (kg == 0) && (li < cnt);
        const int pidx = (int)sidx[w][li];
        const float2 cvv = ((const float2*)cv)[pidx];
        const float e = val ? EXP2(fmaf(lg, 1.44269504f, C_E)) : 0.0f;
        s += e;
        q0 = fmaf(e, cvv.x, q0);
        q1 = fmaf(e, cvv.y, q1);
    }

    // wave reduce + store chunk partial
    #pragma unroll
    for (int off = 1; off < 64; off <<= 1) {
        s  += __shfl_xor(s, off);
        q0 += __shfl_xor(q0, off);
        q1 += __shfl_xor(q1, off);
    }
    if (lane == 0) partials[n*8 + chunk] = make_float4(s, q0, q1, 0.0f);
}

// ==== Path A, kernel A2: reduce chunk partials -> coeff =====================
__global__ __launch_bounds__(256) void attn_coeff_kernel(
    const float4* __restrict__ partials, const float* __restrict__ cv,
    float* __restrict__ coeff_out)
{
    const int n = blockIdx.x * 256 + threadIdx.x;
    float S = 0.0f, Q0 = 0.0f, Q1 = 0.0f;
    #pragma unroll
    for (int c = 0; c < 8; ++c) {
        const float4 P = partials[n*8 + c];
        S += P.x; Q0 += P.y; Q1 += P.z;
    }
    if (!(S > 0.0f)) {   // all masked -> uniform softmax (e=1 per slot)
        S = (float)PP; Q0 = 0.0f; Q1 = 0.0f;
        for (int p = 0; p < PP; ++p) {
            Q0 += cv[2*p]; Q1 += cv[2*p+1];
        }
    }
    const float invS = fast_rcp(S);
    coeff_out[n*2+0] = __expf(-Q0 * invS);
    coeff_out[n*2+1] = __expf(-Q1 * invS);
}

// ======== Path B (fallback, ws too small): R9 attn kernel, verified ========
__global__ __launch_bounds__(256) void attn_kernel(
    const float* __restrict__ pc, const float* __restrict__ cp,
    const float* __restrict__ cv,
    const float* __restrict__ w1, const float* __restrict__ b1,
    const float* __restrict__ w2, const float* __restrict__ b2,
    const float* __restrict__ w3, const float* __restrict__ b3,
    float* __restrict__ coeff_out)
{
    __shared__ float2 scpc[PP];
    __shared__ unsigned short slist[PP];
    __shared__ float sred[16];
    __shared__ int scount;

    const int n = blockIdx.x;
    const int t = threadIdx.x;
    const int wid  = t >> 6;
    const int lane = t & 63;
    const int c15  = lane & 15;
    const int kg   = lane >> 4;
    const int k0   = kg * 8;

    const float b3v = b3[0];

    if (t == 0) scount = 0;

    const float x0 = pc[n*4+0], x1 = pc[n*4+1];
    const float v0 = pc[n*4+2], v1 = pc[n*4+3];
    const float rinv = __builtin_amdgcn_rsqf(v0*v0 + v1*v1 + 1e-16f);
    const float a0 = v0 * rinv, a1 = v1 * rinv;

    union BF { short8 s8; unsigned u[4]; } B0, B1;
    #pragma unroll
    for (int j2 = 0; j2 < 4; ++j2) {
        const int ka = k0 + 2*j2, kb = ka + 1;
        B0.u[j2] = cvt_pk_bf16(w2[ka*32 + c15],      w2[kb*32 + c15]);
        B1.u[j2] = cvt_pk_bf16(w2[ka*32 + c15 + 16], w2[kb*32 + c15 + 16]);
    }
    float b2a[4], b2b[4], w3a[4], w3b[4];
    #pragma unroll
    for (int r = 0; r < 4; ++r) {
        b2a[r] = b2[kg*4 + r];      b2b[r] = b2[16 + kg*4 + r];
        w3a[r] = w3[kg*4 + r];      w3b[r] = w3[16 + kg*4 + r];
    }
    float cfrag[8], w1a[8], w1b[8];
    #pragma unroll
    for (int j = 0; j < 8; ++j) {
        const int k = k0 + j;
        float c = b1[k];
        c = fmaf(x0, w1[0*32+k], c);
        c = fmaf(x1, w1[1*32+k], c);
        c = fmaf(v0, w1[2*32+k], c);
        c = fmaf(v1, w1[3*32+k], c);
        cfrag[j] = c;
        w1a[j] = w1[4*32+k];
        w1b[j] = w1[5*32+k];
    }
    __syncthreads();

    #pragma unroll 1
    for (int i = 0; i < PP/256; ++i) {
        const int p = i*256 + t;
        const float2 cpp = ((const float2*)cp)[p];
        const float r0 = x0 - cpp.x;
        const float r1 = x1 - cpp.y;
        const float pos = fmaf(r0, a0, r1*a1);
        const bool f = pos > 0.0f;
        const unsigned long long mask = __ballot(f);
        int base = 0;
        if (lane == 0 && mask) base = atomicAdd(&scount, __popcll(mask));
        base = __shfl(base, 0);
        if (f) {
            const int idx = base + __popcll(mask & ((1ull << lane) - 1ull));
            const float dist = sqrtf(r0*r0 + r1*r1 + 1e-16f);
            const float angl = pos * fast_rcp(dist + 1e-8f);
            slist[idx] = (unsigned short)p;
            scpc[idx] = make_float2(angl, pos);
        }
    }
    __syncthreads();
    const int M  = scount;
    const int Mt = (M + 15) >> 4;

    #pragma unroll 2
    for (int tile = wid; tile < Mt; tile += 4) {
        const int li = tile*16 + c15;
        const float2 ap = scpc[li < M ? li : 0];
        const float angl = ap.x, pos = ap.y;

        union AF { short8 s8; unsigned u[4]; } H;
        #pragma unroll
        for (int j2 = 0; j2 < 4; ++j2) {
            const float ha = fast_tanh(fmaf(angl, w1a[2*j2+0], fmaf(pos, w1b[2*j2+0], cfrag[2*j2+0])));
            const float hb = fast_tanh(fmaf(angl, w1a[2*j2+1], fmaf(pos, w1b[2*j2+1], cfrag[2*j2+1])));
            H.u[j2] = cvt_pk_bf16(ha, hb);
        }

        f32x4 acca = {b2a[0], b2a[1], b2a[2], b2a[3]};
        f32x4 accb = {b2b[0], b2b[1], b2b[2], b2b[3]};
        acca = __builtin_amdgcn_mfma_f32_16x16x32_bf16(B0.s8, H.s8, acca, 0, 0, 0);
        accb = __builtin_amdgcn_mfma_f32_16x16x32_bf16(B1.s8, H.s8, accb, 0, 0, 0);

        float lg = 0.0f;
        #pragma unroll
        for (int r = 0; r < 4; ++r) {
            lg = fmaf(fast_tanh(acca[r]), w3a[r], lg);
            lg = fmaf(fast_tanh(accb[r]), w3b[r], lg);
        }
        lg += __shfl_xor(lg, 16);
        lg += __shfl_xor(lg, 32);

        if (kg == 0 && li < M) scpc[li].x = lg + b3v;
    }
    __syncthreads();

    float m = -3.4e38f;
    if (M > 0)
        for (int i = t; i < M; i += 256) m = fmaxf(m, scpc[i].x);
    #pragma unroll
    for (int off = 32; off; off >>= 1) m = fmaxf(m, __shfl_xor(m, off));
    if (lane == 0) sred[wid] = m;
    __syncthreads();
    m = fmaxf(fmaxf(sred[0], sred[1]), fmaxf(sred[2], sred[3]));

    float s = 0.0f, q0 = 0.0f, q1 = 0.0f;
    if (M > 0) {
        #pragma unroll 2
        for (int i = t; i < M; i += 256) {
            const float e = EXP2((scpc[i].x - m) * 1.44269504f);
            const float2 cvv = ((const float2*)cv)[slist[i]];
            s += e;
            q0 = fmaf(e, cvv.x, q0);
            q1 = fmaf(e, cvv.y, q1);
        }
    } else {
        for (int i = t; i < PP; i += 256) {
            const float2 cvv = ((const float2*)cv)[i];
            s += 1.0f; q0 += cvv.x; q1 += cvv.y;
        }
    }
    #pragma unroll
    for (int off = 32; off; off >>= 1) {
        s  += __shfl_xor(s, off);
        q0 += __shfl_xor(q0, off);
        q1 += __shfl_xor(q1, off);
    }
    __syncthreads();
    if (lane == 0) {
        sred[4 + wid*3 + 0] = s;
        sred[4 + wid*3 + 1] = q0;
        sred[4 + wid*3 + 2] = q1;
    }
    __syncthreads();
    if (t == 0) {
        float S = 0.0f, Q0 = 0.0f, Q1 = 0.0f;
        #pragma unroll
        for (int w = 0; w < 4; ++w) {
            S  += sred[4 + w*3 + 0];
            Q0 += sred[4 + w*3 + 1];
            Q1 += sred[4 + w*3 + 2];
        }
        const float invS = fast_rcp(S);
        coeff_out[n*2+0] = __expf(-Q0 * invS);
        coeff_out[n*2+1] = __expf(-Q1 * invS);
    }
}

// ------- Kernel C: green MLP via MFMA. Block = 4 rows, wave = 1 row (80 slots) -------
__global__ __launch_bounds__(256) void green_kernel(
    const float* __restrict__ pc,  const float* __restrict__ bc,
    const float* __restrict__ skc, const float* __restrict__ sk,
    const float* __restrict__ vw,
    const float* __restrict__ gw1, const float* __restrict__ gb1,
    const float* __restrict__ gw2, const float* __restrict__ gb2,
    const float* __restrict__ gw3, const float* __restrict__ gb3,
    const float* __restrict__ rw,  const float* __restrict__ rb,
    const float* __restrict__ fw,  const float* __restrict__ fb,
    const float* __restrict__ coeff,
    float* __restrict__ out)
{
    __shared__ unsigned short sinA[GR_ROWS*GR_SLOTS*16];
    __shared__ unsigned short shb[4][16*64];
    __shared__ float swq[GR_SLOTS];
    __shared__ float sg0[4][64];
    __shared__ float squad[4][64];

    const int t = threadIdx.x;
    const int w = t >> 6, lane = t & 63;
    const int c15 = lane & 15, kg = lane >> 4;
    const int n0 = blockIdx.x * GR_ROWS;

    V4 Bw1[4], Bw2[2][4], Bw3[2][4];
    #pragma unroll
    for (int nt = 0; nt < 4; ++nt) {
        const int col = c15 + nt*16;
        #pragma unroll
        for (int j2 = 0; j2 < 4; ++j2) {
            const int ka = kg*8 + 2*j2, kb = ka + 1;
            const float va = (ka < 10) ? gw1[ka*64 + col] : 0.0f;
            const float vb = (kb < 10) ? gw1[kb*64 + col] : 0.0f;
            Bw1[nt].u[j2] = cvt_pk_bf16(va, vb);
        }
        #pragma unroll
        for (int kt = 0; kt < 2; ++kt) {
            #pragma unroll
            for (int j2 = 0; j2 < 4; ++j2) {
                const int ka = kt*32 + kg*8 + 2*j2, kb = ka + 1;
                Bw2[kt][nt].u[j2] = cvt_pk_bf16(gw2[ka*64 + col], gw2[kb*64 + col]);
                Bw3[kt][nt].u[j2] = cvt_pk_bf16(gw3[ka*64 + col], gw3[kb*64 + col]);
            }
        }
    }
    float b1c[4], b2c[4], b3c[4];
    #pragma unroll
    for (int nt = 0; nt < 4; ++nt) {
        b1c[nt] = gb1[c15 + nt*16];
        b2c[nt] = gb2[c15 + nt*16];
        b3c[nt] = gb3[c15 + nt*16];
    }

    for (int row = t; row < GR_ROWS*GR_SLOTS; row += 256) {
        const int nl = row / GR_SLOTS;
        const int s  = row - nl*GR_SLOTS;
        const int n  = n0 + nl;
        u32x4 lo = {0u,0u,0u,0u}, hi = {0u,0u,0u,0u};
        if (s <= 64) {
            const float X0 = pc[n*4+0], X1 = pc[n*4+1];
            const float V0 = pc[n*4+2], V1 = pc[n*4+3];
            const float XP0 = bc[n*4+0], XP1 = bc[n*4+1];
            float I6, I7;
            if (s == 64) { I6 = bc[n*4+2]; I7 = bc[n*4+3]; }
            else         { I6 = skc[s*2+0]; I7 = skc[s*2+1]; }
            const float C0 = coeff[n*2+0], C1 = coeff[n*2+1];
            lo[0] = cvt_pk_bf16(X0, X1);
            lo[1] = cvt_pk_bf16(V0, V1);
            lo[2] = cvt_pk_bf16(XP0, XP1);
            lo[3] = cvt_pk_bf16(I6, I7);
            hi[0] = cvt_pk_bf16(C0, C1);
        }
        ((u32x4*)sinA)[row*2 + 0] = lo;
        ((u32x4*)sinA)[row*2 + 1] = hi;
    }
    if (t < GR_SLOTS)
        swq[t] = (t < QQ) ? (1.0f - sk[t]) * vw[t] : 0.0f;
    __syncthreads();

    unsigned short* hb = &shb[w][0];
    float qacc[4] = {0.f, 0.f, 0.f, 0.f};

    #pragma unroll 1
    for (int T = 0; T < GR_MT; ++T) {
        const int rm = w*GR_SLOTS + T*16 + c15;
        V4 A1; A1.u = (u32x4){0u,0u,0u,0u};
        if (kg < 2) A1.u = ((u32x4*)sinA)[rm*2 + kg];

        f32x4 acc1[4];
        #pragma unroll
        for (int nt = 0; nt < 4; ++nt) {
            f32x4 a = {b1c[nt], b1c[nt], b1c[nt], b1c[nt]};
            acc1[nt] = __builtin_amdgcn_mfma_f32_16x16x32_bf16(A1.s, Bw1[nt].s, a, 0, 0, 0);
        }
        #pragma unroll
        for (int nt = 0; nt < 4; ++nt) {
            #pragma unroll
            for (int r = 0; r < 4; ++r) {
                const int rl = kg*4 + r;
                hb[rl*64 + ((c15 + nt*16) ^ ((rl&7)<<3))] = bf16_bits(fast_tanh(acc1[nt][r]));
            }
        }
        V4 A2[2];
        #pragma unroll
        for (int kt = 0; kt < 2; ++kt)
            A2[kt].u = ((u32x4*)hb)[(c15*64 + ((kt*32 + kg*8) ^ ((c15&7)<<3))) >> 3];
        f32x4 acc2[4];
        #pragma unroll
        for (int nt = 0; nt < 4; ++nt) {
            f32x4 a = {b2c[nt], b2c[nt], b2c[nt], b2c[nt]};
            a = __builtin_amdgcn_mfma_f32_16x16x32_bf16(A2[0].s, Bw2[0][nt].s, a, 0, 0, 0);
            acc2[nt] = __builtin_amdgcn_mfma_f32_16x16x32_bf16(A2[1].s, Bw2[1][nt].s, a, 0, 0, 0);
        }
        #pragma unroll
        for (int nt = 0; nt < 4; ++nt) {
            #pragma unroll
            for (int r = 0; r < 4; ++r) {
                const int rl = kg*4 + r;
                hb[rl*64 + ((c15 + nt*16) ^ ((rl&7)<<3))] = bf16_bits(fast_tanh(acc2[nt][r]));
            }
        }
        V4 A3[2];
        #pragma unroll
        for (int kt = 0; kt < 2; ++kt)
            A3[kt].u = ((u32x4*)hb)[(c15*64 + ((kt*32 + kg*8) ^ ((c15&7)<<3))) >> 3];
        f32x4 acc3[4];
        #pragma unroll
        for (int nt = 0; nt < 4; ++nt) {
            f32x4 a = {b3c[nt], b3c[nt], b3c[nt], b3c[nt]};
            a = __builtin_amdgcn_mfma_f32_16x16x32_bf16(A3[0].s, Bw3[0][nt].s, a, 0, 0, 0);
            acc3[nt] = __builtin_amdgcn_mfma_f32_16x16x32_bf16(A3[1].s, Bw3[1][nt].s, a, 0, 0, 0);
        }
        #pragma unroll
        for (int r = 0; r < 4; ++r) {
            const int s = T*16 + kg*4 + r;
            const float wq = swq[s];
            #pragma unroll
            for (int nt = 0; nt < 4; ++nt) {
                const float g = __expf(fast_tanh(acc3[nt][r]));
                qacc[nt] = fmaf(wq, g, qacc[nt]);
                if (T == GR_MT-1 && kg == 0 && r == 0) sg0[w][c15 + nt*16] = g;
            }
        }
    }

    #pragma unroll
    for (int nt = 0; nt < 4; ++nt) {
        qacc[nt] += __shfl_xor(qacc[nt], 16);
        qacc[nt] += __shfl_xor(qacc[nt], 32);
    }
    if (kg == 0) {
        #pragma unroll
        for (int nt = 0; nt < 4; ++nt) squad[w][c15 + nt*16] = qacc[nt];
    }

    const int k = lane;
    float r0a = rb[k], r1a = 0.f, r2a = 0.f, r3a = 0.f;
    #pragma unroll
    for (int j = 0; j < 64; j += 4) {
        const float4 qd = *(const float4*)&squad[w][j];
        r0a = fmaf(qd.x, rw[(j+0)*64 + k], r0a);
        r1a = fmaf(qd.y, rw[(j+1)*64 + k], r1a);
        r2a = fmaf(qd.z, rw[(j+2)*64 + k], r2a);
        r3a = fmaf(qd.w, rw[(j+3)*64 + k], r3a);
    }
    const float resv = fast_tanh((r0a + r1a) + (r2a + r3a));
    float term = (sg0[w][k] + resv) * fw[k];
    #pragma unroll
    for (int off = 32; off; off >>= 1) term += __shfl_xor(term, off);
    if (lane == 0) out[n0 + w] = term + fb[0];
}

extern "C" void kernel_launch(void* const* d_in, const int* in_sizes, int n_in,
                              void* d_out, int out_size, void* d_ws, size_t ws_size,
                              hipStream_t stream) {
    const float* pc  = (const float*)d_in[0];
    const float* bc  = (const float*)d_in[1];
    const float* cp  = (const float*)d_in[2];
    const float* cv  = (const float*)d_in[3];
    const float* skc = (const float*)d_in[4];
    const float* sk  = (const float*)d_in[5];
    const float* vw  = (const float*)d_in[6];
    const float* aw1 = (const float*)d_in[7];
    const float* ab1 = (const float*)d_in[8];
    const float* aw2 = (const float*)d_in[9];
    const float* ab2 = (const float*)d_in[10];
    const float* aw3 = (const float*)d_in[11];
    const float* ab3 = (const float*)d_in[12];
    const float* gw1 = (const float*)d_in[13];
    const float* gb1 = (const float*)d_in[14];
    const float* gw2 = (const float*)d_in[15];
    const float* gb2 = (const float*)d_in[16];
    const float* gw3 = (const float*)d_in[17];
    const float* gb3 = (const float*)d_in[18];
    const float* rw  = (const float*)d_in[19];
    const float* rb  = (const float*)d_in[20];
    const float* fw  = (const float*)d_in[21];
    const float* fb  = (const float*)d_in[22];

    float* coeff = (float*)d_ws;                       // 16 KB
    float* outp  = (float*)d_out;

    const size_t need = (size_t)NN*2*sizeof(float) + (size_t)NN*8*sizeof(float4);
    if (ws_size >= need) {
        float4* partials = (float4*)((char*)d_ws + (size_t)NN*2*sizeof(float)); // 256 KB
        attn_logits_kernel<<<NN*4, 128, 0, stream>>>(pc, cp, cv, aw1, ab1, aw2, ab2,
                                                     aw3, ab3, partials);
        attn_coeff_kernel<<<NN/256, 256, 0, stream>>>(partials, cv, coeff);
    } else {
        attn_kernel<<<NN, 256, 0, stream>>>(pc, cp, cv, aw1, ab1, aw2, ab2, aw3, ab3, coeff);
    }
    green_kernel<<<NN/GR_ROWS, 256, 0, stream>>>(pc, bc, skc, sk, vw,
                                                 gw1, gb1, gw2, gb2, gw3, gb3,
                                                 rw, rb, fw, fb, coeff, outp);
}

// Round 13
// 93.552 us; speedup vs baseline: 1.1900x; 1.0322x over previous
//
#include <hip/hip_runtime.h>

#define NN 2048
#define PP 2048
#define QQ 64
#define GR_ROWS 4
#define GR_SLOTS 80   // 64 quad + g0(slot 64) + 15 pad
#define GR_MT 5       // 16-row M-tiles per row

typedef __attribute__((ext_vector_type(8))) short short8;
typedef __attribute__((ext_vector_type(4))) float f32x4;
typedef __attribute__((ext_vector_type(4))) unsigned u32x4;

union V4 { u32x4 u; short8 s; };

#if __has_builtin(__builtin_amdgcn_exp2f)
#define EXP2(x) __builtin_amdgcn_exp2f(x)
#else
#define EXP2(x) exp2f(x)
#endif

__device__ __forceinline__ float fast_rcp(float x) { return __builtin_amdgcn_rcpf(x); }

// tanh(x) = 1 - 2/(2^(2x*log2e)+1); saturates for |x| large (rcp(inf)=0)
__device__ __forceinline__ float fast_tanh(float x) {
    float t = EXP2(x * 2.885390082f);
    return 1.0f - 2.0f * __builtin_amdgcn_rcpf(t + 1.0f);
}

// packed f32x2 -> bf16x2 (RNE), single instruction
__device__ __forceinline__ unsigned cvt_pk_bf16(float lo, float hi) {
    unsigned r;
    asm("v_cvt_pk_bf16_f32 %0, %1, %2" : "=v"(r) : "v"(lo), "v"(hi));
    return r;
}
// scalar RNE bf16 bits (for single stores)
__device__ __forceinline__ unsigned short bf16_bits(float f) {
    unsigned u = __builtin_bit_cast(unsigned, f);
    u += 0x7FFFu + ((u >> 16) & 1u);
    return (unsigned short)(u >> 16);
}

// ==== Path A, kernel A1: wave = 256-p chunk; fused fixed-bound softmax partials ====
// grid: 8192 x 128 (2 waves). row n = bid>>2, chunk = (bid&3)*2 + w. No barriers/atomics.
__global__ __launch_bounds__(128) void attn_logits_kernel(
    const float* __restrict__ pc, const float* __restrict__ cp,
    const float* __restrict__ cv,
    const float* __restrict__ w1, const float* __restrict__ b1,
    const float* __restrict__ w2, const float* __restrict__ b2,
    const float* __restrict__ w3, const float* __restrict__ b3,
    float4* __restrict__ partials)   // (NN, 8) chunk partials {s,q0,q1,0}
{
    __shared__ float2 sap[2][272];          // wave-private (angl,pos), +16 zero pad
    __shared__ unsigned short sidx[2][272]; // wave-private p-index

    const int t = threadIdx.x;
    const int w = t >> 6, lane = t & 63;
    const int c15 = lane & 15, kg = lane >> 4;
    const int k0 = kg * 8;
    const int n  = blockIdx.x >> 2;
    const int chunk = (blockIdx.x & 3) * 2 + w;
    const int p0 = chunk * 256;

    const float b3v = b3[0];
    const float x0 = pc[n*4+0], x1 = pc[n*4+1];
    const float v0 = pc[n*4+2], v1 = pc[n*4+3];
    const float rinv = __builtin_amdgcn_rsqf(v0*v0 + v1*v1 + 1e-16f);
    const float a0 = v0 * rinv, a1 = v1 * rinv;

    // ---- step 1: compact survivors of this wave's 256-p chunk ----
    int cnt = 0;
    #pragma unroll
    for (int i = 0; i < 4; ++i) {
        const int p = p0 + i*64 + lane;
        const float2 cpp = ((const float2*)cp)[p];
        const float r0 = x0 - cpp.x;
        const float r1 = x1 - cpp.y;
        const float pos = fmaf(r0, a0, r1*a1);
        const bool f = pos > 0.0f;
        const unsigned long long mask = __ballot(f);
        if (f) {
            const int idx = cnt + __popcll(mask & ((1ull << lane) - 1ull));
            const float dist = sqrtf(r0*r0 + r1*r1 + 1e-16f);
            const float angl = pos * fast_rcp(dist + 1e-8f);
            sap[w][idx]  = make_float2(angl, pos);
            sidx[w][idx] = (unsigned short)p;
        }
        cnt += __popcll(mask);              // wave-uniform
    }
    // pad 16 entries so tile loads never need an index select
    if (lane < 16) {
        sap[w][cnt + lane]  = make_float2(0.0f, 0.0f);
        sidx[w][cnt + lane] = 0;
    }

    // ---- row-invariant fragments ----
    union BF { short8 s8; unsigned u[4]; } B0, B1;
    #pragma unroll
    for (int j2 = 0; j2 < 4; ++j2) {
        const int ka = k0 + 2*j2, kb = ka + 1;
        B0.u[j2] = cvt_pk_bf16(w2[ka*32 + c15],      w2[kb*32 + c15]);
        B1.u[j2] = cvt_pk_bf16(w2[ka*32 + c15 + 16], w2[kb*32 + c15 + 16]);
    }
    float b2a[4], b2b[4], w3a[4], w3b[4];
    #pragma unroll
    for (int r = 0; r < 4; ++r) {
        b2a[r] = b2[kg*4 + r];      b2b[r] = b2[16 + kg*4 + r];
        w3a[r] = w3[kg*4 + r];      w3b[r] = w3[16 + kg*4 + r];
    }
    float cfrag[8], w1a[8], w1b[8];
    #pragma unroll
    for (int j = 0; j < 8; ++j) {
        const int k = k0 + j;
        float c = b1[k];
        c = fmaf(x0, w1[0*32+k], c);
        c = fmaf(x1, w1[1*32+k], c);
        c = fmaf(v0, w1[2*32+k], c);
        c = fmaf(v1, w1[3*32+k], c);
        cfrag[j] = c;
        w1a[j] = w1[4*32+k];
        w1b[j] = w1[5*32+k];
    }
    // rigorous logit bound: |lg - b3| <= sum|w3| (|tanh|<1); e = exp2(lg*l2e + C_E) <= 1
    float sw3 = 0.0f;
    #pragma unroll
    for (int j = 0; j < 32; ++j) sw3 += fabsf(w3[j]);
    const float Lb = fabsf(b3v) + sw3;
    const float C_E = (b3v - Lb) * 1.44269504f;

    // ---- step 2: MFMA tiles over survivors; accumulate softmax partials ----
    float s = 0.0f, q0 = 0.0f, q1 = 0.0f;
    const int nt = (cnt + 15) >> 4;
    #pragma unroll 2
    for (int tile = 0; tile < nt; ++tile) {
        const int li = tile*16 + c15;
        const float2 ap = sap[w][li];       // padded: always in-bounds
        const float angl = ap.x, pos = ap.y;

        float pre[8], h[8];
        #pragma unroll
        for (int j = 0; j < 8; ++j)
            pre[j] = fmaf(angl, w1a[j], fmaf(pos, w1b[j], cfrag[j]));
        #pragma unroll
        for (int j = 0; j < 8; ++j) h[j] = fast_tanh(pre[j]);

        union AF { short8 s8; unsigned u[4]; } H;
        #pragma unroll
        for (int j2 = 0; j2 < 4; ++j2)
            H.u[j2] = cvt_pk_bf16(h[2*j2], h[2*j2+1]);

        // D = W2^T · H1^T : col = pair (c15), row = neuron (kg*4+r)
        f32x4 acca = {b2a[0], b2a[1], b2a[2], b2a[3]};
        f32x4 accb = {b2b[0], b2b[1], b2b[2], b2b[3]};
        acca = __builtin_amdgcn_mfma_f32_16x16x32_bf16(B0.s8, H.s8, acca, 0, 0, 0);
        accb = __builtin_amdgcn_mfma_f32_16x16x32_bf16(B1.s8, H.s8, accb, 0, 0, 0);

        float lg = 0.0f;
        #pragma unroll
        for (int r = 0; r < 4; ++r) {
            lg = fmaf(fast_tanh(acca[r]), w3a[r], lg);
            lg = fmaf(fast_tanh(accb[r]), w3b[r], lg);
        }
        lg += __shfl_xor(lg, 16);
        lg += __shfl_xor(lg, 32);   // full logit partial for pair c15 in all lanes

        const bool val = (kg == 0) && (li < cnt);
        const int pidx = (int)sidx[w][li];
        const float2 cvv = ((const float2*)cv)[pidx];
        const float e = val ? EXP2(fmaf(lg, 1.44269504f, C_E)) : 0.0f;
        s += e;
        q0 = fmaf(e, cvv.x, q0);
        q1 = fmaf(e, cvv.y, q1);
    }

    // wave reduce + store chunk partial
    #pragma unroll
    for (int off = 1; off < 64; off <<= 1) {
        s  += __shfl_xor(s, off);
        q0 += __shfl_xor(q0, off);
        q1 += __shfl_xor(q1, off);
    }
    if (lane == 0) partials[n*8 + chunk] = make_float4(s, q0, q1, 0.0f);
}

// ======== Path B (fallback, ws too small): R9 attn kernel, verified ========
__global__ __launch_bounds__(256) void attn_kernel(
    const float* __restrict__ pc, const float* __restrict__ cp,
    const float* __restrict__ cv,
    const float* __restrict__ w1, const float* __restrict__ b1,
    const float* __restrict__ w2, const float* __restrict__ b2,
    const float* __restrict__ w3, const float* __restrict__ b3,
    float* __restrict__ coeff_out)
{
    __shared__ float2 scpc[PP];
    __shared__ unsigned short slist[PP];
    __shared__ float sred[16];
    __shared__ int scount;

    const int n = blockIdx.x;
    const int t = threadIdx.x;
    const int wid  = t >> 6;
    const int lane = t & 63;
    const int c15  = lane & 15;
    const int kg   = lane >> 4;
    const int k0   = kg * 8;

    const float b3v = b3[0];

    if (t == 0) scount = 0;

    const float x0 = pc[n*4+0], x1 = pc[n*4+1];
    const float v0 = pc[n*4+2], v1 = pc[n*4+3];
    const float rinv = __builtin_amdgcn_rsqf(v0*v0 + v1*v1 + 1e-16f);
    const float a0 = v0 * rinv, a1 = v1 * rinv;

    union BF { short8 s8; unsigned u[4]; } B0, B1;
    #pragma unroll
    for (int j2 = 0; j2 < 4; ++j2) {
        const int ka = k0 + 2*j2, kb = ka + 1;
        B0.u[j2] = cvt_pk_bf16(w2[ka*32 + c15],      w2[kb*32 + c15]);
        B1.u[j2] = cvt_pk_bf16(w2[ka*32 + c15 + 16], w2[kb*32 + c15 + 16]);
    }
    float b2a[4], b2b[4], w3a[4], w3b[4];
    #pragma unroll
    for (int r = 0; r < 4; ++r) {
        b2a[r] = b2[kg*4 + r];      b2b[r] = b2[16 + kg*4 + r];
        w3a[r] = w3[kg*4 + r];      w3b[r] = w3[16 + kg*4 + r];
    }
    float cfrag[8], w1a[8], w1b[8];
    #pragma unroll
    for (int j = 0; j < 8; ++j) {
        const int k = k0 + j;
        float c = b1[k];
        c = fmaf(x0, w1[0*32+k], c);
        c = fmaf(x1, w1[1*32+k], c);
        c = fmaf(v0, w1[2*32+k], c);
        c = fmaf(v1, w1[3*32+k], c);
        cfrag[j] = c;
        w1a[j] = w1[4*32+k];
        w1b[j] = w1[5*32+k];
    }
    __syncthreads();

    #pragma unroll 1
    for (int i = 0; i < PP/256; ++i) {
        const int p = i*256 + t;
        const float2 cpp = ((const float2*)cp)[p];
        const float r0 = x0 - cpp.x;
        const float r1 = x1 - cpp.y;
        const float pos = fmaf(r0, a0, r1*a1);
        const bool f = pos > 0.0f;
        const unsigned long long mask = __ballot(f);
        int base = 0;
        if (lane == 0 && mask) base = atomicAdd(&scount, __popcll(mask));
        base = __shfl(base, 0);
        if (f) {
            const int idx = base + __popcll(mask & ((1ull << lane) - 1ull));
            const float dist = sqrtf(r0*r0 + r1*r1 + 1e-16f);
            const float angl = pos * fast_rcp(dist + 1e-8f);
            slist[idx] = (unsigned short)p;
            scpc[idx] = make_float2(angl, pos);
        }
    }
    __syncthreads();
    const int M  = scount;
    const int Mt = (M + 15) >> 4;

    #pragma unroll 2
    for (int tile = wid; tile < Mt; tile += 4) {
        const int li = tile*16 + c15;
        const float2 ap = scpc[li < M ? li : 0];
        const float angl = ap.x, pos = ap.y;

        union AF { short8 s8; unsigned u[4]; } H;
        #pragma unroll
        for (int j2 = 0; j2 < 4; ++j2) {
            const float ha = fast_tanh(fmaf(angl, w1a[2*j2+0], fmaf(pos, w1b[2*j2+0], cfrag[2*j2+0])));
            const float hb = fast_tanh(fmaf(angl, w1a[2*j2+1], fmaf(pos, w1b[2*j2+1], cfrag[2*j2+1])));
            H.u[j2] = cvt_pk_bf16(ha, hb);
        }

        f32x4 acca = {b2a[0], b2a[1], b2a[2], b2a[3]};
        f32x4 accb = {b2b[0], b2b[1], b2b[2], b2b[3]};
        acca = __builtin_amdgcn_mfma_f32_16x16x32_bf16(B0.s8, H.s8, acca, 0, 0, 0);
        accb = __builtin_amdgcn_mfma_f32_16x16x32_bf16(B1.s8, H.s8, accb, 0, 0, 0);

        float lg = 0.0f;
        #pragma unroll
        for (int r = 0; r < 4; ++r) {
            lg = fmaf(fast_tanh(acca[r]), w3a[r], lg);
            lg = fmaf(fast_tanh(accb[r]), w3b[r], lg);
        }
        lg += __shfl_xor(lg, 16);
        lg += __shfl_xor(lg, 32);

        if (kg == 0 && li < M) scpc[li].x = lg + b3v;
    }
    __syncthreads();

    float m = -3.4e38f;
    if (M > 0)
        for (int i = t; i < M; i += 256) m = fmaxf(m, scpc[i].x);
    #pragma unroll
    for (int off = 32; off; off >>= 1) m = fmaxf(m, __shfl_xor(m, off));
    if (lane == 0) sred[wid] = m;
    __syncthreads();
    m = fmaxf(fmaxf(sred[0], sred[1]), fmaxf(sred[2], sred[3]));

    float s = 0.0f, q0 = 0.0f, q1 = 0.0f;
    if (M > 0) {
        #pragma unroll 2
        for (int i = t; i < M; i += 256) {
            const float e = EXP2((scpc[i].x - m) * 1.44269504f);
            const float2 cvv = ((const float2*)cv)[slist[i]];
            s += e;
            q0 = fmaf(e, cvv.x, q0);
            q1 = fmaf(e, cvv.y, q1);
        }
    } else {
        for (int i = t; i < PP; i += 256) {
            const float2 cvv = ((const float2*)cv)[i];
            s += 1.0f; q0 += cvv.x; q1 += cvv.y;
        }
    }
    #pragma unroll
    for (int off = 32; off; off >>= 1) {
        s  += __shfl_xor(s, off);
        q0 += __shfl_xor(q0, off);
        q1 += __shfl_xor(q1, off);
    }
    __syncthreads();
    if (lane == 0) {
        sred[4 + wid*3 + 0] = s;
        sred[4 + wid*3 + 1] = q0;
        sred[4 + wid*3 + 2] = q1;
    }
    __syncthreads();
    if (t == 0) {
        float S = 0.0f, Q0 = 0.0f, Q1 = 0.0f;
        #pragma unroll
        for (int w = 0; w < 4; ++w) {
            S  += sred[4 + w*3 + 0];
            Q0 += sred[4 + w*3 + 1];
            Q1 += sred[4 + w*3 + 2];
        }
        const float invS = fast_rcp(S);
        coeff_out[n*2+0] = __expf(-Q0 * invS);
        coeff_out[n*2+1] = __expf(-Q1 * invS);
    }
}

// ------- Kernel C: green MLP via MFMA; coeff computed in-block from partials -------
__global__ __launch_bounds__(256) void green_kernel(
    const float* __restrict__ pc,  const float* __restrict__ bc,
    const float* __restrict__ skc, const float* __restrict__ sk,
    const float* __restrict__ vw,
    const float* __restrict__ gw1, const float* __restrict__ gb1,
    const float* __restrict__ gw2, const float* __restrict__ gb2,
    const float* __restrict__ gw3, const float* __restrict__ gb3,
    const float* __restrict__ rw,  const float* __restrict__ rb,
    const float* __restrict__ fw,  const float* __restrict__ fb,
    const float4* __restrict__ partials,  // (NN,8) chunk partials (Path A)
    const float* __restrict__ cv,
    const float* __restrict__ coeff_in,   // (NN,2) coeff (Path B)
    const int use_partials,
    float* __restrict__ out)
{
    __shared__ unsigned short sinA[GR_ROWS*GR_SLOTS*16];
    __shared__ unsigned short shb[4][16*64];
    __shared__ float swq[GR_SLOTS];
    __shared__ float sg0[4][64];
    __shared__ float squad[4][64];
    __shared__ float scoef[GR_ROWS][2];

    const int t = threadIdx.x;
    const int w = t >> 6, lane = t & 63;
    const int c15 = lane & 15, kg = lane >> 4;
    const int n0 = blockIdx.x * GR_ROWS;

    // ---- step 0: coeff for the block's 4 rows ----
    if (use_partials) {
        if (t < 32) {                      // wave 0: lane = row*8 + chunk
            const int row = t >> 3, c = t & 7;
            const float4 P = partials[(n0 + row)*8 + c];
            float S = P.x, Q0 = P.y, Q1 = P.z;
            S  += __shfl_xor(S, 1);  S  += __shfl_xor(S, 2);  S  += __shfl_xor(S, 4);
            Q0 += __shfl_xor(Q0, 1); Q0 += __shfl_xor(Q0, 2); Q0 += __shfl_xor(Q0, 4);
            Q1 += __shfl_xor(Q1, 1); Q1 += __shfl_xor(Q1, 2); Q1 += __shfl_xor(Q1, 4);
            if (c == 0) {
                if (!(S > 0.0f)) {         // all masked -> uniform softmax (never in practice)
                    S = (float)PP; Q0 = 0.0f; Q1 = 0.0f;
                    for (int p = 0; p < PP; ++p) { Q0 += cv[2*p]; Q1 += cv[2*p+1]; }
                }
                const float invS = fast_rcp(S);
                scoef[row][0] = __expf(-Q0 * invS);
                scoef[row][1] = __expf(-Q1 * invS);
            }
        }
    } else {
        if (t < GR_ROWS*2) scoef[t >> 1][t & 1] = coeff_in[(n0 + (t >> 1))*2 + (t & 1)];
    }
    __syncthreads();

    // ---- weight fragments (per lane, loop-invariant) ----
    V4 Bw1[4], Bw2[2][4], Bw3[2][4];
    #pragma unroll
    for (int nt = 0; nt < 4; ++nt) {
        const int col = c15 + nt*16;
        #pragma unroll
        for (int j2 = 0; j2 < 4; ++j2) {
            const int ka = kg*8 + 2*j2, kb = ka + 1;
            const float va = (ka < 10) ? gw1[ka*64 + col] : 0.0f;
            const float vb = (kb < 10) ? gw1[kb*64 + col] : 0.0f;
            Bw1[nt].u[j2] = cvt_pk_bf16(va, vb);
        }
        #pragma unroll
        for (int kt = 0; kt < 2; ++kt) {
            #pragma unroll
            for (int j2 = 0; j2 < 4; ++j2) {
                const int ka = kt*32 + kg*8 + 2*j2, kb = ka + 1;
                Bw2[kt][nt].u[j2] = cvt_pk_bf16(gw2[ka*64 + col], gw2[kb*64 + col]);
                Bw3[kt][nt].u[j2] = cvt_pk_bf16(gw3[ka*64 + col], gw3[kb*64 + col]);
            }
        }
    }
    float b1c[4], b2c[4], b3c[4];
    #pragma unroll
    for (int nt = 0; nt < 4; ++nt) {
        b1c[nt] = gb1[c15 + nt*16];
        b2c[nt] = gb2[c15 + nt*16];
        b3c[nt] = gb3[c15 + nt*16];
    }

    // ---- G1: build bf16 input rows [4 rows x 80 slots][16] ----
    for (int row = t; row < GR_ROWS*GR_SLOTS; row += 256) {
        const int nl = row / GR_SLOTS;
        const int s  = row - nl*GR_SLOTS;
        const int n  = n0 + nl;
        u32x4 lo = {0u,0u,0u,0u}, hi = {0u,0u,0u,0u};
        if (s <= 64) {
            const float X0 = pc[n*4+0], X1 = pc[n*4+1];
            const float V0 = pc[n*4+2], V1 = pc[n*4+3];
            const float XP0 = bc[n*4+0], XP1 = bc[n*4+1];
            float I6, I7;
            if (s == 64) { I6 = bc[n*4+2]; I7 = bc[n*4+3]; }
            else         { I6 = skc[s*2+0]; I7 = skc[s*2+1]; }
            const float C0 = scoef[nl][0], C1 = scoef[nl][1];
            lo[0] = cvt_pk_bf16(X0, X1);
            lo[1] = cvt_pk_bf16(V0, V1);
            lo[2] = cvt_pk_bf16(XP0, XP1);
            lo[3] = cvt_pk_bf16(I6, I7);
            hi[0] = cvt_pk_bf16(C0, C1);
        }
        ((u32x4*)sinA)[row*2 + 0] = lo;
        ((u32x4*)sinA)[row*2 + 1] = hi;
    }
    if (t < GR_SLOTS)
        swq[t] = (t < QQ) ? (1.0f - sk[t]) * vw[t] : 0.0f;
    __syncthreads();

    // ---- G2: per wave, 5 M-tiles of its row ----
    unsigned short* hb = &shb[w][0];
    float qacc[4] = {0.f, 0.f, 0.f, 0.f};

    #pragma unroll 1
    for (int T = 0; T < GR_MT; ++T) {
        const int rm = w*GR_SLOTS + T*16 + c15;
        V4 A1; A1.u = (u32x4){0u,0u,0u,0u};
        if (kg < 2) A1.u = ((u32x4*)sinA)[rm*2 + kg];

        f32x4 acc1[4];
        #pragma unroll
        for (int nt = 0; nt < 4; ++nt) {
            f32x4 a = {b1c[nt], b1c[nt], b1c[nt], b1c[nt]};
            acc1[nt] = __builtin_amdgcn_mfma_f32_16x16x32_bf16(A1.s, Bw1[nt].s, a, 0, 0, 0);
        }
        #pragma unroll
        for (int nt = 0; nt < 4; ++nt) {
            #pragma unroll
            for (int r = 0; r < 4; ++r) {
                const int rl = kg*4 + r;
                hb[rl*64 + ((c15 + nt*16) ^ ((rl&7)<<3))] = bf16_bits(fast_tanh(acc1[nt][r]));
            }
        }
        V4 A2[2];
        #pragma unroll
        for (int kt = 0; kt < 2; ++kt)
            A2[kt].u = ((u32x4*)hb)[(c15*64 + ((kt*32 + kg*8) ^ ((c15&7)<<3))) >> 3];
        f32x4 acc2[4];
        #pragma unroll
        for (int nt = 0; nt < 4; ++nt) {
            f32x4 a = {b2c[nt], b2c[nt], b2c[nt], b2c[nt]};
            a = __builtin_amdgcn_mfma_f32_16x16x32_bf16(A2[0].s, Bw2[0][nt].s, a, 0, 0, 0);
            acc2[nt] = __builtin_amdgcn_mfma_f32_16x16x32_bf16(A2[1].s, Bw2[1][nt].s, a, 0, 0, 0);
        }
        #pragma unroll
        for (int nt = 0; nt < 4; ++nt) {
            #pragma unroll
            for (int r = 0; r < 4; ++r) {
                const int rl = kg*4 + r;
                hb[rl*64 + ((c15 + nt*16) ^ ((rl&7)<<3))] = bf16_bits(fast_tanh(acc2[nt][r]));
            }
        }
        V4 A3[2];
        #pragma unroll
        for (int kt = 0; kt < 2; ++kt)
            A3[kt].u = ((u32x4*)hb)[(c15*64 + ((kt*32 + kg*8) ^ ((c15&7)<<3))) >> 3];
        f32x4 acc3[4];
        #pragma unroll
        for (int nt = 0; nt < 4; ++nt) {
            f32x4 a = {b3c[nt], b3c[nt], b3c[nt], b3c[nt]};
            a = __builtin_amdgcn_mfma_f32_16x16x32_bf16(A3[0].s, Bw3[0][nt].s, a, 0, 0, 0);
            acc3[nt] = __builtin_amdgcn_mfma_f32_16x16x32_bf16(A3[1].s, Bw3[1][nt].s, a, 0, 0, 0);
        }
        #pragma unroll
        for (int r = 0; r < 4; ++r) {
            const int s = T*16 + kg*4 + r;
            const float wq = swq[s];
            #pragma unroll
            for (int nt = 0; nt < 4; ++nt) {
                const float g = __expf(fast_tanh(acc3[nt][r]));
                qacc[nt] = fmaf(wq, g, qacc[nt]);
                if (T == GR_MT-1 && kg == 0 && r == 0) sg0[w][c15 + nt*16] = g;
            }
        }
    }

    #pragma unroll
    for (int nt = 0; nt < 4; ++nt) {
        qacc[nt] += __shfl_xor(qacc[nt], 16);
        qacc[nt] += __shfl_xor(qacc[nt], 32);
    }
    if (kg == 0) {
        #pragma unroll
        for (int nt = 0; nt < 4; ++nt) squad[w][c15 + nt*16] = qacc[nt];
    }

    const int k = lane;
    float r0a = rb[k], r1a = 0.f, r2a = 0.f, r3a = 0.f;
    #pragma unroll
    for (int j = 0; j < 64; j += 4) {
        const float4 qd = *(const float4*)&squad[w][j];
        r0a = fmaf(qd.x, rw[(j+0)*64 + k], r0a);
        r1a = fmaf(qd.y, rw[(j+1)*64 + k], r1a);
        r2a = fmaf(qd.z, rw[(j+2)*64 + k], r2a);
        r3a = fmaf(qd.w, rw[(j+3)*64 + k], r3a);
    }
    const float resv = fast_tanh((r0a + r1a) + (r2a + r3a));
    float term = (sg0[w][k] + resv) * fw[k];
    #pragma unroll
    for (int off = 32; off; off >>= 1) term += __shfl_xor(term, off);
    if (lane == 0) out[n0 + w] = term + fb[0];
}

extern "C" void kernel_launch(void* const* d_in, const int* in_sizes, int n_in,
                              void* d_out, int out_size, void* d_ws, size_t ws_size,
                              hipStream_t stream) {
    const float* pc  = (const float*)d_in[0];
    const float* bc  = (const float*)d_in[1];
    const float* cp  = (const float*)d_in[2];
    const float* cv  = (const float*)d_in[3];
    const float* skc = (const float*)d_in[4];
    const float* sk  = (const float*)d_in[5];
    const float* vw  = (const float*)d_in[6];
    const float* aw1 = (const float*)d_in[7];
    const float* ab1 = (const float*)d_in[8];
    const float* aw2 = (const float*)d_in[9];
    const float* ab2 = (const float*)d_in[10];
    const float* aw3 = (const float*)d_in[11];
    const float* ab3 = (const float*)d_in[12];
    const float* gw1 = (const float*)d_in[13];
    const float* gb1 = (const float*)d_in[14];
    const float* gw2 = (const float*)d_in[15];
    const float* gb2 = (const float*)d_in[16];
    const float* gw3 = (const float*)d_in[17];
    const float* gb3 = (const float*)d_in[18];
    const float* rw  = (const float*)d_in[19];
    const float* rb  = (const float*)d_in[20];
    const float* fw  = (const float*)d_in[21];
    const float* fb  = (const float*)d_in[22];

    float* coeff = (float*)d_ws;                       // 16 KB (Path B only)
    float* outp  = (float*)d_out;

    const size_t need = (size_t)NN*2*sizeof(float) + (size_t)NN*8*sizeof(float4);
    if (ws_size >= need) {
        float4* partials = (float4*)((char*)d_ws + (size_t)NN*2*sizeof(float)); // 256 KB
        attn_logits_kernel<<<NN*4, 128, 0, stream>>>(pc, cp, cv, aw1, ab1, aw2, ab2,
                                                     aw3, ab3, partials);
        green_kernel<<<NN/GR_ROWS, 256, 0, stream>>>(pc, bc, skc, sk, vw,
                                                     gw1, gb1, gw2, gb2, gw3, gb3,
                                                     rw, rb, fw, fb,
                                                     partials, cv, coeff, 1, outp);
    } else {
        attn_kernel<<<NN, 256, 0, stream>>>(pc, cp, cv, aw1, ab1, aw2, ab2, aw3, ab3, coeff);
        green_kernel<<<NN/GR_ROWS, 256, 0, stream>>>(pc, bc, skc, sk, vw,
                                                     gw1, gb1, gw2, gb2, gw3, gb3,
                                                     rw, rb, fw, fb,
                                                     (const float4*)d_ws, cv, coeff, 0, outp);
    }
}

// Round 14
// 80.195 us; speedup vs baseline: 1.3882x; 1.1666x over previous
//
#include <hip/hip_runtime.h>

#define NN 2048
#define PP 2048
#define QQ 64
#define GR_ROWS 4
#define GR_SLOTS 80   // 64 quad + g0(slot 64) + 15 pad
#define GR_MT 5       // 16-row M-tiles per row

typedef __attribute__((ext_vector_type(8))) short short8;
typedef __attribute__((ext_vector_type(4))) float f32x4;
typedef __attribute__((ext_vector_type(4))) unsigned u32x4;

union V4 { u32x4 u; short8 s; };

#if __has_builtin(__builtin_amdgcn_exp2f)
#define EXP2(x) __builtin_amdgcn_exp2f(x)
#else
#define EXP2(x) exp2f(x)
#endif

__device__ __forceinline__ float fast_rcp(float x) { return __builtin_amdgcn_rcpf(x); }

// tanh(x) = 1 - 2/(2^(2x*log2e)+1); saturates for |x| large (rcp(inf)=0)
__device__ __forceinline__ float fast_tanh(float x) {
    float t = EXP2(x * 2.885390082f);
    return 1.0f - 2.0f * __builtin_amdgcn_rcpf(t + 1.0f);
}

// packed f32x2 -> bf16x2 (RNE), single instruction
__device__ __forceinline__ unsigned cvt_pk_bf16(float lo, float hi) {
    unsigned r;
    asm("v_cvt_pk_bf16_f32 %0, %1, %2" : "=v"(r) : "v"(lo), "v"(hi));
    return r;
}
// scalar RNE bf16 bits (for single stores)
__device__ __forceinline__ unsigned short bf16_bits(float f) {
    unsigned u = __builtin_bit_cast(unsigned, f);
    u += 0x7FFFu + ((u >> 16) & 1u);
    return (unsigned short)(u >> 16);
}

// ==== Kernel A: block = one row (512 thr, 8 waves); wave = 256-p chunk ====
// Per-wave compaction + MFMA tiles + fused fixed-bound softmax; block-reduce -> coeff.
// No atomics; all LDS wave-private except the final sred.
__global__ __launch_bounds__(512) void attn_kernel(
    const float* __restrict__ pc, const float* __restrict__ cp,
    const float* __restrict__ cv,
    const float* __restrict__ w1, const float* __restrict__ b1,
    const float* __restrict__ w2, const float* __restrict__ b2,
    const float* __restrict__ w3, const float* __restrict__ b3,
    float* __restrict__ coeff_out)   // (NN,2)
{
    __shared__ float2 sap[8][272];          // wave-private (angl,pos), +16 zero pad
    __shared__ unsigned short sidx[8][272]; // wave-private p-index
    __shared__ float sred[24];

    const int t = threadIdx.x;
    const int w = t >> 6, lane = t & 63;
    const int c15 = lane & 15, kg = lane >> 4;
    const int k0 = kg * 8;
    const int n  = blockIdx.x;
    const int p0 = w * 256;                 // wave w owns chunk w

    const float b3v = b3[0];
    const float x0 = pc[n*4+0], x1 = pc[n*4+1];
    const float v0 = pc[n*4+2], v1 = pc[n*4+3];
    const float rinv = __builtin_amdgcn_rsqf(v0*v0 + v1*v1 + 1e-16f);
    const float a0 = v0 * rinv, a1 = v1 * rinv;

    // ---- step 1: compact survivors of this wave's 256-p chunk ----
    int cnt = 0;
    #pragma unroll
    for (int i = 0; i < 4; ++i) {
        const int p = p0 + i*64 + lane;
        const float2 cpp = ((const float2*)cp)[p];
        const float r0 = x0 - cpp.x;
        const float r1 = x1 - cpp.y;
        const float pos = fmaf(r0, a0, r1*a1);
        const bool f = pos > 0.0f;
        const unsigned long long mask = __ballot(f);
        if (f) {
            const int idx = cnt + __popcll(mask & ((1ull << lane) - 1ull));
            const float dist = sqrtf(r0*r0 + r1*r1 + 1e-16f);
            const float angl = pos * fast_rcp(dist + 1e-8f);
            sap[w][idx]  = make_float2(angl, pos);
            sidx[w][idx] = (unsigned short)p;
        }
        cnt += __popcll(mask);              // wave-uniform
    }
    // pad 16 entries so tile loads never need an index select
    if (lane < 16) {
        sap[w][cnt + lane]  = make_float2(0.0f, 0.0f);
        sidx[w][cnt + lane] = 0;
    }

    // ---- row-invariant fragments ----
    union BF { short8 s8; unsigned u[4]; } B0, B1;
    #pragma unroll
    for (int j2 = 0; j2 < 4; ++j2) {
        const int ka = k0 + 2*j2, kb = ka + 1;
        B0.u[j2] = cvt_pk_bf16(w2[ka*32 + c15],      w2[kb*32 + c15]);
        B1.u[j2] = cvt_pk_bf16(w2[ka*32 + c15 + 16], w2[kb*32 + c15 + 16]);
    }
    float b2a[4], b2b[4], w3a[4], w3b[4];
    #pragma unroll
    for (int r = 0; r < 4; ++r) {
        b2a[r] = b2[kg*4 + r];      b2b[r] = b2[16 + kg*4 + r];
        w3a[r] = w3[kg*4 + r];      w3b[r] = w3[16 + kg*4 + r];
    }
    float cfrag[8], w1a[8], w1b[8];
    #pragma unroll
    for (int j = 0; j < 8; ++j) {
        const int k = k0 + j;
        float c = b1[k];
        c = fmaf(x0, w1[0*32+k], c);
        c = fmaf(x1, w1[1*32+k], c);
        c = fmaf(v0, w1[2*32+k], c);
        c = fmaf(v1, w1[3*32+k], c);
        cfrag[j] = c;
        w1a[j] = w1[4*32+k];
        w1b[j] = w1[5*32+k];
    }
    // rigorous logit bound: |lg - b3| <= sum|w3| (|tanh|<1); e = exp2(lg*l2e + C_E) <= 1
    float sw3 = 0.0f;
    #pragma unroll
    for (int j = 0; j < 32; ++j) sw3 += fabsf(w3[j]);
    const float Lb = fabsf(b3v) + sw3;
    const float C_E = (b3v - Lb) * 1.44269504f;

    // ---- step 2: MFMA tiles over survivors; accumulate fused softmax partials ----
    float s = 0.0f, q0 = 0.0f, q1 = 0.0f;
    const int nt = (cnt + 15) >> 4;
    #pragma unroll 2
    for (int tile = 0; tile < nt; ++tile) {
        const int li = tile*16 + c15;
        const float2 ap = sap[w][li];       // padded: always in-bounds
        const float angl = ap.x, pos = ap.y;

        float pre[8], h[8];
        #pragma unroll
        for (int j = 0; j < 8; ++j)
            pre[j] = fmaf(angl, w1a[j], fmaf(pos, w1b[j], cfrag[j]));
        #pragma unroll
        for (int j = 0; j < 8; ++j) h[j] = fast_tanh(pre[j]);

        union AF { short8 s8; unsigned u[4]; } H;
        #pragma unroll
        for (int j2 = 0; j2 < 4; ++j2)
            H.u[j2] = cvt_pk_bf16(h[2*j2], h[2*j2+1]);

        // D = W2^T · H1^T : col = pair (c15), row = neuron (kg*4+r)
        f32x4 acca = {b2a[0], b2a[1], b2a[2], b2a[3]};
        f32x4 accb = {b2b[0], b2b[1], b2b[2], b2b[3]};
        acca = __builtin_amdgcn_mfma_f32_16x16x32_bf16(B0.s8, H.s8, acca, 0, 0, 0);
        accb = __builtin_amdgcn_mfma_f32_16x16x32_bf16(B1.s8, H.s8, accb, 0, 0, 0);

        float lg = 0.0f;
        #pragma unroll
        for (int r = 0; r < 4; ++r) {
            lg = fmaf(fast_tanh(acca[r]), w3a[r], lg);
            lg = fmaf(fast_tanh(accb[r]), w3b[r], lg);
        }
        lg += __shfl_xor(lg, 16);
        lg += __shfl_xor(lg, 32);   // full logit partial for pair c15 in all lanes

        const bool val = (kg == 0) && (li < cnt);
        const int pidx = (int)sidx[w][li];
        const float2 cvv = ((const float2*)cv)[pidx];
        const float e = val ? EXP2(fmaf(lg, 1.44269504f, C_E)) : 0.0f;
        s += e;
        q0 = fmaf(e, cvv.x, q0);
        q1 = fmaf(e, cvv.y, q1);
    }

    // ---- step 3: wave reduce, then block reduce over 8 waves -> coeff ----
    #pragma unroll
    for (int off = 1; off < 64; off <<= 1) {
        s  += __shfl_xor(s, off);
        q0 += __shfl_xor(q0, off);
        q1 += __shfl_xor(q1, off);
    }
    if (lane == 0) {
        sred[w*3 + 0] = s;
        sred[w*3 + 1] = q0;
        sred[w*3 + 2] = q1;
    }
    __syncthreads();
    if (t == 0) {
        float S = 0.0f, Q0 = 0.0f, Q1 = 0.0f;
        #pragma unroll
        for (int i = 0; i < 8; ++i) {
            S  += sred[i*3 + 0];
            Q0 += sred[i*3 + 1];
            Q1 += sred[i*3 + 2];
        }
        if (!(S > 0.0f)) {   // all masked -> uniform softmax (e=1 per slot)
            S = (float)PP; Q0 = 0.0f; Q1 = 0.0f;
            for (int p = 0; p < PP; ++p) { Q0 += cv[2*p]; Q1 += cv[2*p+1]; }
        }
        const float invS = fast_rcp(S);
        coeff_out[n*2+0] = __expf(-Q0 * invS);
        coeff_out[n*2+1] = __expf(-Q1 * invS);
    }
}

// ------- Kernel C: green MLP via MFMA. Block = 4 rows, wave = 1 row (80 slots) -------
__global__ __launch_bounds__(256) void green_kernel(
    const float* __restrict__ pc,  const float* __restrict__ bc,
    const float* __restrict__ skc, const float* __restrict__ sk,
    const float* __restrict__ vw,
    const float* __restrict__ gw1, const float* __restrict__ gb1,
    const float* __restrict__ gw2, const float* __restrict__ gb2,
    const float* __restrict__ gw3, const float* __restrict__ gb3,
    const float* __restrict__ rw,  const float* __restrict__ rb,
    const float* __restrict__ fw,  const float* __restrict__ fb,
    const float* __restrict__ coeff,
    float* __restrict__ out)
{
    __shared__ unsigned short sinA[GR_ROWS*GR_SLOTS*16];
    __shared__ unsigned short shb[4][16*64];
    __shared__ float swq[GR_SLOTS];
    __shared__ float sg0[4][64];
    __shared__ float squad[4][64];

    const int t = threadIdx.x;
    const int w = t >> 6, lane = t & 63;
    const int c15 = lane & 15, kg = lane >> 4;
    const int n0 = blockIdx.x * GR_ROWS;

    V4 Bw1[4], Bw2[2][4], Bw3[2][4];
    #pragma unroll
    for (int nt = 0; nt < 4; ++nt) {
        const int col = c15 + nt*16;
        #pragma unroll
        for (int j2 = 0; j2 < 4; ++j2) {
            const int ka = kg*8 + 2*j2, kb = ka + 1;
            const float va = (ka < 10) ? gw1[ka*64 + col] : 0.0f;
            const float vb = (kb < 10) ? gw1[kb*64 + col] : 0.0f;
            Bw1[nt].u[j2] = cvt_pk_bf16(va, vb);
        }
        #pragma unroll
        for (int kt = 0; kt < 2; ++kt) {
            #pragma unroll
            for (int j2 = 0; j2 < 4; ++j2) {
                const int ka = kt*32 + kg*8 + 2*j2, kb = ka + 1;
                Bw2[kt][nt].u[j2] = cvt_pk_bf16(gw2[ka*64 + col], gw2[kb*64 + col]);
                Bw3[kt][nt].u[j2] = cvt_pk_bf16(gw3[ka*64 + col], gw3[kb*64 + col]);
            }
        }
    }
    float b1c[4], b2c[4], b3c[4];
    #pragma unroll
    for (int nt = 0; nt < 4; ++nt) {
        b1c[nt] = gb1[c15 + nt*16];
        b2c[nt] = gb2[c15 + nt*16];
        b3c[nt] = gb3[c15 + nt*16];
    }

    for (int row = t; row < GR_ROWS*GR_SLOTS; row += 256) {
        const int nl = row / GR_SLOTS;
        const int s  = row - nl*GR_SLOTS;
        const int n  = n0 + nl;
        u32x4 lo = {0u,0u,0u,0u}, hi = {0u,0u,0u,0u};
        if (s <= 64) {
            const float X0 = pc[n*4+0], X1 = pc[n*4+1];
            const float V0 = pc[n*4+2], V1 = pc[n*4+3];
            const float XP0 = bc[n*4+0], XP1 = bc[n*4+1];
            float I6, I7;
            if (s == 64) { I6 = bc[n*4+2]; I7 = bc[n*4+3]; }
            else         { I6 = skc[s*2+0]; I7 = skc[s*2+1]; }
            const float C0 = coeff[n*2+0], C1 = coeff[n*2+1];
            lo[0] = cvt_pk_bf16(X0, X1);
            lo[1] = cvt_pk_bf16(V0, V1);
            lo[2] = cvt_pk_bf16(XP0, XP1);
            lo[3] = cvt_pk_bf16(I6, I7);
            hi[0] = cvt_pk_bf16(C0, C1);
        }
        ((u32x4*)sinA)[row*2 + 0] = lo;
        ((u32x4*)sinA)[row*2 + 1] = hi;
    }
    if (t < GR_SLOTS)
        swq[t] = (t < QQ) ? (1.0f - sk[t]) * vw[t] : 0.0f;
    __syncthreads();

    unsigned short* hb = &shb[w][0];
    float qacc[4] = {0.f, 0.f, 0.f, 0.f};

    #pragma unroll 1
    for (int T = 0; T < GR_MT; ++T) {
        const int rm = w*GR_SLOTS + T*16 + c15;
        V4 A1; A1.u = (u32x4){0u,0u,0u,0u};
        if (kg < 2) A1.u = ((u32x4*)sinA)[rm*2 + kg];

        f32x4 acc1[4];
        #pragma unroll
        for (int nt = 0; nt < 4; ++nt) {
            f32x4 a = {b1c[nt], b1c[nt], b1c[nt], b1c[nt]};
            acc1[nt] = __builtin_amdgcn_mfma_f32_16x16x32_bf16(A1.s, Bw1[nt].s, a, 0, 0, 0);
        }
        #pragma unroll
        for (int nt = 0; nt < 4; ++nt) {
            #pragma unroll
            for (int r = 0; r < 4; ++r) {
                const int rl = kg*4 + r;
                hb[rl*64 + ((c15 + nt*16) ^ ((rl&7)<<3))] = bf16_bits(fast_tanh(acc1[nt][r]));
            }
        }
        V4 A2[2];
        #pragma unroll
        for (int kt = 0; kt < 2; ++kt)
            A2[kt].u = ((u32x4*)hb)[(c15*64 + ((kt*32 + kg*8) ^ ((c15&7)<<3))) >> 3];
        f32x4 acc2[4];
        #pragma unroll
        for (int nt = 0; nt < 4; ++nt) {
            f32x4 a = {b2c[nt], b2c[nt], b2c[nt], b2c[nt]};
            a = __builtin_amdgcn_mfma_f32_16x16x32_bf16(A2[0].s, Bw2[0][nt].s, a, 0, 0, 0);
            acc2[nt] = __builtin_amdgcn_mfma_f32_16x16x32_bf16(A2[1].s, Bw2[1][nt].s, a, 0, 0, 0);
        }
        #pragma unroll
        for (int nt = 0; nt < 4; ++nt) {
            #pragma unroll
            for (int r = 0; r < 4; ++r) {
                const int rl = kg*4 + r;
                hb[rl*64 + ((c15 + nt*16) ^ ((rl&7)<<3))] = bf16_bits(fast_tanh(acc2[nt][r]));
            }
        }
        V4 A3[2];
        #pragma unroll
        for (int kt = 0; kt < 2; ++kt)
            A3[kt].u = ((u32x4*)hb)[(c15*64 + ((kt*32 + kg*8) ^ ((c15&7)<<3))) >> 3];
        f32x4 acc3[4];
        #pragma unroll
        for (int nt = 0; nt < 4; ++nt) {
            f32x4 a = {b3c[nt], b3c[nt], b3c[nt], b3c[nt]};
            a = __builtin_amdgcn_mfma_f32_16x16x32_bf16(A3[0].s, Bw3[0][nt].s, a, 0, 0, 0);
            acc3[nt] = __builtin_amdgcn_mfma_f32_16x16x32_bf16(A3[1].s, Bw3[1][nt].s, a, 0, 0, 0);
        }
        #pragma unroll
        for (int r = 0; r < 4; ++r) {
            const int s = T*16 + kg*4 + r;
            const float wq = swq[s];
            #pragma unroll
            for (int nt = 0; nt < 4; ++nt) {
                const float g = __expf(fast_tanh(acc3[nt][r]));
                qacc[nt] = fmaf(wq, g, qacc[nt]);
                if (T == GR_MT-1 && kg == 0 && r == 0) sg0[w][c15 + nt*16] = g;
            }
        }
    }

    #pragma unroll
    for (int nt = 0; nt < 4; ++nt) {
        qacc[nt] += __shfl_xor(qacc[nt], 16);
        qacc[nt] += __shfl_xor(qacc[nt], 32);
    }
    if (kg == 0) {
        #pragma unroll
        for (int nt = 0; nt < 4; ++nt) squad[w][c15 + nt*16] = qacc[nt];
    }

    const int k = lane;
    float r0a = rb[k], r1a = 0.f, r2a = 0.f, r3a = 0.f;
    #pragma unroll
    for (int j = 0; j < 64; j += 4) {
        const float4 qd = *(const float4*)&squad[w][j];
        r0a = fmaf(qd.x, rw[(j+0)*64 + k], r0a);
        r1a = fmaf(qd.y, rw[(j+1)*64 + k], r1a);
        r2a = fmaf(qd.z, rw[(j+2)*64 + k], r2a);
        r3a = fmaf(qd.w, rw[(j+3)*64 + k], r3a);
    }
    const float resv = fast_tanh((r0a + r1a) + (r2a + r3a));
    float term = (sg0[w][k] + resv) * fw[k];
    #pragma unroll
    for (int off = 32; off; off >>= 1) term += __shfl_xor(term, off);
    if (lane == 0) out[n0 + w] = term + fb[0];
}

extern "C" void kernel_launch(void* const* d_in, const int* in_sizes, int n_in,
                              void* d_out, int out_size, void* d_ws, size_t ws_size,
                              hipStream_t stream) {
    const float* pc  = (const float*)d_in[0];
    const float* bc  = (const float*)d_in[1];
    const float* cp  = (const float*)d_in[2];
    const float* cv  = (const float*)d_in[3];
    const float* skc = (const float*)d_in[4];
    const float* sk  = (const float*)d_in[5];
    const float* vw  = (const float*)d_in[6];
    const float* aw1 = (const float*)d_in[7];
    const float* ab1 = (const float*)d_in[8];
    const float* aw2 = (const float*)d_in[9];
    const float* ab2 = (const float*)d_in[10];
    const float* aw3 = (const float*)d_in[11];
    const float* ab3 = (const float*)d_in[12];
    const float* gw1 = (const float*)d_in[13];
    const float* gb1 = (const float*)d_in[14];
    const float* gw2 = (const float*)d_in[15];
    const float* gb2 = (const float*)d_in[16];
    const float* gw3 = (const float*)d_in[17];
    const float* gb3 = (const float*)d_in[18];
    const float* rw  = (const float*)d_in[19];
    const float* rb  = (const float*)d_in[20];
    const float* fw  = (const float*)d_in[21];
    const float* fb  = (const float*)d_in[22];

    float* coeff = (float*)d_ws;          // N*2 floats = 16 KB (known-safe)
    float* outp  = (float*)d_out;

    attn_kernel<<<NN, 512, 0, stream>>>(pc, cp, cv, aw1, ab1, aw2, ab2, aw3, ab3, coeff);
    green_kernel<<<NN/GR_ROWS, 256, 0, stream>>>(pc, bc, skc, sk, vw,
                                                 gw1, gb1, gw2, gb2, gw3, gb3,
                                                 rw, rb, fw, fb, coeff, outp);
}